// Round 1
// baseline (1155.800 us; speedup 1.0000x reference)
//
#include <hip/hip_runtime.h>
#include <cstddef>
#include <cstdint>

#define NN 150000
#define EP 400000
#define EN 200000

__device__ __forceinline__ float fast_tanh(float x) {
    float e = __expf(2.f * x);
    return 1.f - 2.f / (e + 1.f);   // x->-inf: -1 ; x->+inf: 1 ; no NaN
}

// ---------------- counts & inverse counts ----------------
__global__ void count_kernel(const int* __restrict__ dst, int E, int* __restrict__ cnt) {
    int e = blockIdx.x * blockDim.x + threadIdx.x;
    if (e < E) atomicAdd(&cnt[dst[e]], 1);
}

__global__ void inv_kernel(const int* __restrict__ cp, const int* __restrict__ cn,
                           float* __restrict__ invp, float* __restrict__ invn, int n) {
    int i = blockIdx.x * blockDim.x + threadIdx.x;
    if (i < n) {
        int a = cp[i]; if (a < 1) a = 1;
        int b = cn[i]; if (b < 1) b = 1;
        invp[i] = 1.f / (float)a;
        invn[i] = 1.f / (float)b;
    }
}

// ---------------- pack block-structured weights ----------------
__global__ void pack_weights(const float* __restrict__ W1p, const float* __restrict__ b1p,
                             const float* __restrict__ W1n, const float* __restrict__ b1n,
                             const float* __restrict__ W2p, const float* __restrict__ b2p,
                             const float* __restrict__ W2n, const float* __restrict__ b2n,
                             float* __restrict__ Wcat1, float* __restrict__ Wloc1,
                             float* __restrict__ bcat1,
                             float* __restrict__ W2cat, float* __restrict__ b2cat) {
    int idx = blockIdx.x * blockDim.x + threadIdx.x;
    if (idx < 128 * 128) {
        int r = idx >> 7, j = idx & 127;
        Wcat1[idx] = (j < 64) ? W1p[r * 64 + j] : W1n[r * 64 + (j - 64)];
        Wloc1[idx] = (j < 64) ? W1p[(128 + r) * 64 + j] : W1n[(128 + r) * 64 + (j - 64)];
    }
    if (idx < 128) {
        bcat1[idx] = (idx < 64) ? b1p[idx] : b1n[idx - 64];
        b2cat[idx] = (idx < 64) ? b2p[idx] : b2n[idx - 64];
    }
    if (idx < 384 * 128) {
        int r = idx >> 7, j = idx & 127;
        float v = 0.f;
        if (r < 64)       { if (j < 64)  v = W2p[r * 64 + j]; }                      // pp -> out_p
        else if (r < 128) { if (j >= 64) v = W2n[(r - 64) * 64 + (j - 64)]; }        // pn -> out_n
        else if (r < 192) { if (j >= 64) v = W2n[(64 + r - 128) * 64 + (j - 64)]; }  // np -> out_n
        else if (r < 256) { if (j < 64)  v = W2p[(64 + r - 192) * 64 + j]; }         // nn -> out_p
        else if (r < 320) { if (j < 64)  v = W2p[(128 + r - 256) * 64 + j]; }        // zp -> out_p
        else              { if (j >= 64) v = W2n[(128 + r - 320) * 64 + (j - 64)]; } // zn -> out_n
        W2cat[idx] = v;
    }
}

// ---------------- scatter mean (atomic) ----------------
template<int SHIFT>
__global__ void scatter_mean(const float* __restrict__ feat, const int* __restrict__ src,
                             const int* __restrict__ dst, int E, int c0,
                             const float* __restrict__ inv, float* __restrict__ out, int oc0) {
    int gid = blockIdx.x * blockDim.x + threadIdx.x;
    int e = gid >> SHIFT;
    if (e >= E) return;
    int c = gid & ((1 << SHIFT) - 1);
    int s = src[e], d = dst[e];
    float v = feat[(size_t)s * 128 + c0 + c] * inv[d];
    atomicAdd(&out[(size_t)d * 128 + oc0 + c], v);
}

// ---------------- generic fp32 GEMM, M=128 fixed ----------------
// out[n x 128] = act( Aseg(n x K) @ W(K x 128) [+bias] [+addend] )
// BNIN: A elements transformed by relu((a-mu)*rstd*g+be) at load.
// STATS: accumulate per-column sum & sumsq of the (pre-activation) output into stats[256] (double).
template<int K, int NSEG, bool BIAS, bool TANH_ACT, bool ADDEND, bool BNIN, bool STATS>
__global__ __launch_bounds__(256) void gemm128(
    const float* __restrict__ A0, const float* __restrict__ A1, const float* __restrict__ A2,
    const float* __restrict__ W, const float* __restrict__ bias,
    const float* __restrict__ addend,
    const float* __restrict__ mu, const float* __restrict__ rstd,
    const float* __restrict__ gamma, const float* __restrict__ beta,
    double* __restrict__ stats, float* __restrict__ out, int n)
{
    constexpr int SEGW = K / NSEG;
    constexpr int BM = 64, BK = 32;
    __shared__ float a_lds[BM][BK + 1];
    __shared__ float w_lds[BK][128];
    const int tid = threadIdx.x;
    const int cg = tid & 15;   // col group: cols cg*8 .. cg*8+7
    const int rg = tid >> 4;   // row group: rows rg*4 .. rg*4+3
    const int brow = blockIdx.x * BM;

    float acc[4][8];
#pragma unroll
    for (int i = 0; i < 4; ++i)
#pragma unroll
        for (int j = 0; j < 8; ++j) acc[i][j] = 0.f;

    for (int k0 = 0; k0 < K; k0 += BK) {
        const float* As;
        int kloc;
        if (NSEG == 1) { As = A0; kloc = k0; }
        else {
            int s = k0 >> 7;
            As = (s == 0) ? A0 : ((s == 1) ? A1 : A2);
            kloc = k0 & 127;
        }
        // stage A: 64 rows x 32 k
#pragma unroll
        for (int i = 0; i < 2; ++i) {
            int lin = tid + i * 256;
            int r = lin >> 3;
            int kq = lin & 7;
            int row = brow + r;
            float4 v = make_float4(0.f, 0.f, 0.f, 0.f);
            if (row < n) {
                v = *reinterpret_cast<const float4*>(&As[(size_t)row * SEGW + kloc + kq * 4]);
                if (BNIN) {
                    int kb = kloc + kq * 4;
                    v.x = fmaxf((v.x - mu[kb + 0]) * rstd[kb + 0] * gamma[kb + 0] + beta[kb + 0], 0.f);
                    v.y = fmaxf((v.y - mu[kb + 1]) * rstd[kb + 1] * gamma[kb + 1] + beta[kb + 1], 0.f);
                    v.z = fmaxf((v.z - mu[kb + 2]) * rstd[kb + 2] * gamma[kb + 2] + beta[kb + 2], 0.f);
                    v.w = fmaxf((v.w - mu[kb + 3]) * rstd[kb + 3] * gamma[kb + 3] + beta[kb + 3], 0.f);
                }
            }
            a_lds[r][kq * 4 + 0] = v.x;
            a_lds[r][kq * 4 + 1] = v.y;
            a_lds[r][kq * 4 + 2] = v.z;
            a_lds[r][kq * 4 + 3] = v.w;
        }
        // stage W: 32 k x 128 cols
#pragma unroll
        for (int i = 0; i < 4; ++i) {
            int lin = tid + i * 256;
            int kk = lin >> 5;
            int c4 = lin & 31;
            *reinterpret_cast<float4*>(&w_lds[kk][c4 * 4]) =
                *reinterpret_cast<const float4*>(&W[(size_t)(k0 + kk) * 128 + c4 * 4]);
        }
        __syncthreads();
#pragma unroll
        for (int kk = 0; kk < BK; ++kk) {
            float4 w0 = *reinterpret_cast<const float4*>(&w_lds[kk][cg * 8]);
            float4 w1 = *reinterpret_cast<const float4*>(&w_lds[kk][cg * 8 + 4]);
            float wv[8] = {w0.x, w0.y, w0.z, w0.w, w1.x, w1.y, w1.z, w1.w};
#pragma unroll
            for (int i = 0; i < 4; ++i) {
                float a = a_lds[rg * 4 + i][kk];
#pragma unroll
                for (int j = 0; j < 8; ++j) acc[i][j] = fmaf(a, wv[j], acc[i][j]);
            }
        }
        __syncthreads();
    }

    // epilogue
#pragma unroll
    for (int i = 0; i < 4; ++i) {
        int row = brow + rg * 4 + i;
        bool ok = row < n;
#pragma unroll
        for (int j = 0; j < 8; ++j) {
            int col = cg * 8 + j;
            float v = acc[i][j];
            if (BIAS) v += bias[col];
            if (ADDEND) { if (ok) v += addend[(size_t)row * 128 + col]; }
            if (TANH_ACT) v = fast_tanh(v);
            acc[i][j] = v;
        }
        if (ok) {
            float4 o0 = make_float4(acc[i][0], acc[i][1], acc[i][2], acc[i][3]);
            float4 o1 = make_float4(acc[i][4], acc[i][5], acc[i][6], acc[i][7]);
            *reinterpret_cast<float4*>(&out[(size_t)row * 128 + cg * 8 + 0]) = o0;
            *reinterpret_cast<float4*>(&out[(size_t)row * 128 + cg * 8 + 4]) = o1;
        }
    }

    if (STATS) {
        __shared__ float red[16][128];
#pragma unroll
        for (int j = 0; j < 8; ++j) {
            float s = 0.f;
#pragma unroll
            for (int i = 0; i < 4; ++i)
                if (brow + rg * 4 + i < n) s += acc[i][j];
            red[rg][cg * 8 + j] = s;
        }
        __syncthreads();
        if (tid < 128) {
            float s = 0.f;
#pragma unroll
            for (int r = 0; r < 16; ++r) s += red[r][tid];
            atomicAdd(&stats[tid], (double)s);
        }
        __syncthreads();
#pragma unroll
        for (int j = 0; j < 8; ++j) {
            float s = 0.f;
#pragma unroll
            for (int i = 0; i < 4; ++i)
                if (brow + rg * 4 + i < n) s += acc[i][j] * acc[i][j];
            red[rg][cg * 8 + j] = s;
        }
        __syncthreads();
        if (tid < 128) {
            float s = 0.f;
#pragma unroll
            for (int r = 0; r < 16; ++r) s += red[r][tid];
            atomicAdd(&stats[128 + tid], (double)s);
        }
    }
}

__global__ void bn_finalize(const double* __restrict__ stats,
                            float* __restrict__ mu, float* __restrict__ rstd, int n) {
    int c = threadIdx.x;
    if (c < 128) {
        double m = stats[c] / (double)n;
        double var = stats[128 + c] / (double)n - m * m;
        mu[c] = (float)m;
        rstd[c] = rsqrtf((float)var + 1e-5f);
    }
}

// prob = sigmoid( relu(BN(M2)) @ Wm3 + bm3 )  — one wave per row
__global__ void gemv_prob(const float* __restrict__ M2,
                          const float* __restrict__ mu, const float* __restrict__ rstd,
                          const float* __restrict__ g, const float* __restrict__ be,
                          const float* __restrict__ Wm3, const float* __restrict__ bm3,
                          float* __restrict__ outp, int n) {
    int wid = (int)((blockIdx.x * (size_t)blockDim.x + threadIdx.x) >> 6);
    int lane = threadIdx.x & 63;
    if (wid >= n) return;
    float s = 0.f;
#pragma unroll
    for (int t = 0; t < 2; ++t) {
        int k = lane + t * 64;
        float a = M2[(size_t)wid * 128 + k];
        a = fmaxf((a - mu[k]) * rstd[k] * g[k] + be[k], 0.f);
        s += a * Wm3[k];
    }
#pragma unroll
    for (int off = 32; off > 0; off >>= 1) s += __shfl_down(s, off);
    if (lane == 0) outp[wid] = 1.f / (1.f + __expf(-(s + bm3[0])));
}

extern "C" void kernel_launch(void* const* d_in, const int* in_sizes, int n_in,
                              void* d_out, int out_size, void* d_ws, size_t ws_size,
                              hipStream_t stream) {
    const float* x   = (const float*)d_in[0];
    const int*   pos = (const int*)d_in[1];
    const int*   neg = (const int*)d_in[2];
    const float* W_in = (const float*)d_in[3];
    const float* b_in = (const float*)d_in[4];
    const float* W1p = (const float*)d_in[5];
    const float* b1p = (const float*)d_in[6];
    const float* W1n = (const float*)d_in[7];
    const float* b1n = (const float*)d_in[8];
    const float* W2p = (const float*)d_in[9];
    const float* b2p = (const float*)d_in[10];
    const float* W2n = (const float*)d_in[11];
    const float* b2n = (const float*)d_in[12];
    const float* Wz  = (const float*)d_in[13];
    const float* bz  = (const float*)d_in[14];
    const float* Wm1 = (const float*)d_in[15];
    const float* bm1 = (const float*)d_in[16];
    const float* g1  = (const float*)d_in[17];
    const float* be1 = (const float*)d_in[18];
    const float* Wm2 = (const float*)d_in[19];
    const float* bm2 = (const float*)d_in[20];
    const float* g2  = (const float*)d_in[21];
    const float* be2 = (const float*)d_in[22];
    const float* Wm3 = (const float*)d_in[23];
    const float* bm3 = (const float*)d_in[24];

    char* ws = (char*)d_ws;
    size_t off = 0;
    auto carve = [&](size_t bytes) -> void* {
        void* p = (void*)(ws + off);
        off = (off + bytes + 255) & ~(size_t)255;
        return p;
    };
    const size_t NB = (size_t)NN * 128 * sizeof(float);
    float* bufA  = (float*)carve(NB);
    float* bufB  = (float*)carve(NB);
    float* bufC  = (float*)carve(NB);
    int*   cnt_p = (int*)carve(NN * sizeof(int));
    int*   cnt_n = (int*)carve(NN * sizeof(int));
    float* invp  = (float*)carve(NN * sizeof(float));
    float* invn  = (float*)carve(NN * sizeof(float));
    float* Wcat1 = (float*)carve(128 * 128 * sizeof(float));
    float* Wloc1 = (float*)carve(128 * 128 * sizeof(float));
    float* bcat1 = (float*)carve(128 * sizeof(float));
    float* W2cat = (float*)carve(384 * 128 * sizeof(float));
    float* b2cat = (float*)carve(128 * sizeof(float));
    double* stats1 = (double*)carve(256 * sizeof(double));
    double* stats2 = (double*)carve(256 * sizeof(double));
    float* mu1   = (float*)carve(128 * sizeof(float));
    float* rstd1 = (float*)carve(128 * sizeof(float));
    float* mu2   = (float*)carve(128 * sizeof(float));
    float* rstd2 = (float*)carve(128 * sizeof(float));
    (void)ws_size; (void)in_sizes; (void)n_in; (void)out_size;

    float* zout = (float*)d_out;                    // N x 128
    float* pout = zout + (size_t)NN * 128;          // N

    const int GB = (NN + 63) / 64;                  // gemm blocks

    // counts
    hipMemsetAsync(cnt_p, 0, NN * sizeof(int), stream);
    hipMemsetAsync(cnt_n, 0, NN * sizeof(int), stream);
    count_kernel<<<(EP + 255) / 256, 256, 0, stream>>>(pos + EP, EP, cnt_p);
    count_kernel<<<(EN + 255) / 256, 256, 0, stream>>>(neg + EN, EN, cnt_n);
    inv_kernel<<<(NN + 255) / 256, 256, 0, stream>>>(cnt_p, cnt_n, invp, invn, NN);
    pack_weights<<<192, 256, 0, stream>>>(W1p, b1p, W1n, b1n, W2p, b2p, W2n, b2n,
                                          Wcat1, Wloc1, bcat1, W2cat, b2cat);

    // h = x @ W_in + b_in  -> A
    gemm128<64, 1, true, false, false, false, false><<<GB, 256, 0, stream>>>(
        x, nullptr, nullptr, W_in, b_in, nullptr, nullptr, nullptr, nullptr, nullptr,
        nullptr, bufA, NN);

    // U1 = h @ Wcat1 -> B
    gemm128<128, 1, false, false, false, false, false><<<GB, 256, 0, stream>>>(
        bufA, nullptr, nullptr, Wcat1, nullptr, nullptr, nullptr, nullptr, nullptr, nullptr,
        nullptr, bufB, NN);

    // C = [mean_pos(U1[:, :64]) | mean_neg(U1[:, 64:])]
    hipMemsetAsync(bufC, 0, NB, stream);
    scatter_mean<6><<<(EP * 64 + 255) / 256, 256, 0, stream>>>(bufB, pos, pos + EP, EP, 0, invp, bufC, 0);
    scatter_mean<6><<<(EN * 64 + 255) / 256, 256, 0, stream>>>(bufB, neg, neg + EN, EN, 64, invn, bufC, 64);

    // z1 = tanh(C + h @ Wloc1 + bcat1) -> C
    gemm128<128, 1, true, true, true, false, false><<<GB, 256, 0, stream>>>(
        bufA, nullptr, nullptr, Wloc1, bcat1, bufC, nullptr, nullptr, nullptr, nullptr,
        nullptr, bufC, NN);

    // P = mean_pos(z1) -> A ; Q = mean_neg(z1) -> B
    hipMemsetAsync(bufA, 0, NB, stream);
    hipMemsetAsync(bufB, 0, NB, stream);
    scatter_mean<7><<<(EP * 128 + 255) / 256, 256, 0, stream>>>(bufC, pos, pos + EP, EP, 0, invp, bufA, 0);
    scatter_mean<7><<<(EN * 128 + 255) / 256, 256, 0, stream>>>(bufC, neg, neg + EN, EN, 0, invn, bufB, 0);

    // z2 = tanh([P|Q|z1] @ W2cat + b2cat) -> A (in-place over P, row-owned)
    gemm128<384, 3, true, true, false, false, false><<<GB, 256, 0, stream>>>(
        bufA, bufB, bufC, W2cat, b2cat, nullptr, nullptr, nullptr, nullptr, nullptr,
        nullptr, bufA, NN);

    // z = tanh(z2 @ Wz + bz) -> d_out (first N*128)
    gemm128<128, 1, true, true, false, false, false><<<GB, 256, 0, stream>>>(
        bufA, nullptr, nullptr, Wz, bz, nullptr, nullptr, nullptr, nullptr, nullptr,
        nullptr, zout, NN);

    // M1 = z @ Wm1 + bm1 -> B (+stats1)
    hipMemsetAsync(stats1, 0, 256 * sizeof(double), stream);
    hipMemsetAsync(stats2, 0, 256 * sizeof(double), stream);
    gemm128<128, 1, true, false, false, false, true><<<GB, 256, 0, stream>>>(
        zout, nullptr, nullptr, Wm1, bm1, nullptr, nullptr, nullptr, nullptr, nullptr,
        stats1, bufB, NN);
    bn_finalize<<<1, 128, 0, stream>>>(stats1, mu1, rstd1, NN);

    // M2 = relu(BN(M1)) @ Wm2 + bm2 -> A (+stats2)
    gemm128<128, 1, true, false, false, true, true><<<GB, 256, 0, stream>>>(
        bufB, nullptr, nullptr, Wm2, bm2, nullptr, mu1, rstd1, g1, be1,
        stats2, bufA, NN);
    bn_finalize<<<1, 128, 0, stream>>>(stats2, mu2, rstd2, NN);

    // prob = sigmoid(relu(BN(M2)) @ Wm3 + bm3) -> d_out tail
    gemv_prob<<<(NN + 3) / 4, 256, 0, stream>>>(bufA, mu2, rstd2, g2, be2, Wm3, bm3, pout, NN);
}

// Round 2
// 996.091 us; speedup vs baseline: 1.1603x; 1.1603x over previous
//
#include <hip/hip_runtime.h>
#include <hip/hip_bf16.h>
#include <cstddef>
#include <cstdint>

#define NN 150000
#define EP 400000
#define EN 200000

typedef __bf16 bf16x8 __attribute__((ext_vector_type(8)));
typedef float  f32x4  __attribute__((ext_vector_type(4)));

__device__ __forceinline__ float fast_tanh(float x) {
    float e = __expf(2.f * x);
    return 1.f - 2.f / (e + 1.f);
}

// ---------------- counts & inverse counts ----------------
__global__ void count_kernel(const int* __restrict__ dst, int E, int* __restrict__ cnt) {
    int e = blockIdx.x * blockDim.x + threadIdx.x;
    if (e < E) atomicAdd(&cnt[dst[e]], 1);
}

__global__ void inv_kernel(const int* __restrict__ cp, const int* __restrict__ cn,
                           float* __restrict__ invp, float* __restrict__ invn, int n) {
    int i = blockIdx.x * blockDim.x + threadIdx.x;
    if (i < n) {
        int a = cp[i]; if (a < 1) a = 1;
        int b = cn[i]; if (b < 1) b = 1;
        invp[i] = 1.f / (float)a;
        invn[i] = 1.f / (float)b;
    }
}

// ---------------- weight prep: pack + transpose to [col][k] bf16 ----------------
__global__ void prep_weights(const float* __restrict__ W_in,
                             const float* __restrict__ W1p, const float* __restrict__ b1p,
                             const float* __restrict__ W1n, const float* __restrict__ b1n,
                             const float* __restrict__ W2p, const float* __restrict__ b2p,
                             const float* __restrict__ W2n, const float* __restrict__ b2n,
                             const float* __restrict__ Wz,  const float* __restrict__ Wm1,
                             const float* __restrict__ Wm2,
                             __hip_bfloat16* __restrict__ WtIn,  // [128][64]
                             __hip_bfloat16* __restrict__ WtC1,  // [128][128]
                             __hip_bfloat16* __restrict__ WtL1,  // [128][128]
                             __hip_bfloat16* __restrict__ Wt2,   // [128][384]
                             __hip_bfloat16* __restrict__ WtZ,
                             __hip_bfloat16* __restrict__ WtM1,
                             __hip_bfloat16* __restrict__ WtM2,
                             float* __restrict__ bcat1, float* __restrict__ b2cat) {
    int idx = blockIdx.x * blockDim.x + threadIdx.x;
    if (idx < 128 * 64) {
        int c = idx >> 6, k = idx & 63;
        WtIn[idx] = __float2bfloat16(W_in[k * 128 + c]);
    }
    if (idx < 128 * 128) {
        int c = idx >> 7, k = idx & 127;
        float v1 = (c < 64) ? W1p[k * 64 + c] : W1n[k * 64 + (c - 64)];
        WtC1[idx] = __float2bfloat16(v1);
        float v2 = (c < 64) ? W1p[(128 + k) * 64 + c] : W1n[(128 + k) * 64 + (c - 64)];
        WtL1[idx] = __float2bfloat16(v2);
        WtZ[idx]  = __float2bfloat16(Wz[k * 128 + c]);
        WtM1[idx] = __float2bfloat16(Wm1[k * 128 + c]);
        WtM2[idx] = __float2bfloat16(Wm2[k * 128 + c]);
    }
    if (idx < 128 * 384) {
        int c = idx / 384, r = idx % 384;
        float v = 0.f;
        if (r < 64)       { if (c < 64)  v = W2p[r * 64 + c]; }
        else if (r < 128) { if (c >= 64) v = W2n[(r - 64) * 64 + (c - 64)]; }
        else if (r < 192) { if (c >= 64) v = W2n[(64 + r - 128) * 64 + (c - 64)]; }
        else if (r < 256) { if (c < 64)  v = W2p[(64 + r - 192) * 64 + c]; }
        else if (r < 320) { if (c < 64)  v = W2p[(128 + r - 256) * 64 + c]; }
        else              { if (c >= 64) v = W2n[(128 + r - 320) * 64 + (c - 64)]; }
        Wt2[idx] = __float2bfloat16(v);
    }
    if (idx < 128) {
        bcat1[idx] = (idx < 64) ? b1p[idx] : b1n[idx - 64];
        b2cat[idx] = (idx < 64) ? b2p[idx] : b2n[idx - 64];
    }
}

// ---------------- scatter mean (atomic, bf16 gather) ----------------
template<int SHIFT>
__global__ void scatter_mean_bf16(const __hip_bfloat16* __restrict__ feat,
                                  const int* __restrict__ src, const int* __restrict__ dst,
                                  int E, int c0, const float* __restrict__ inv,
                                  float* __restrict__ out, int oc0) {
    int gid = blockIdx.x * blockDim.x + threadIdx.x;
    int e = gid >> SHIFT;
    if (e >= E) return;
    int c = gid & ((1 << SHIFT) - 1);
    int s = src[e], d = dst[e];
    float v = __bfloat162float(feat[(size_t)s * 128 + c0 + c]) * inv[d];
    atomicAdd(&out[(size_t)d * 128 + oc0 + c], v);
}

// ---------------- bf16 MFMA GEMM, N=128 fixed ----------------
// out[n x 128] = act( A(n x K) @ W(K x 128) [+bias] [+addend] )
// A given as NSEG segments of width K/NSEG; bit s of F32MASK => segment s is fp32
// (converted to bf16 in the fragment loader), else bf16.
// BNIN: A elements transformed by relu((a-mu)*rstd*g+be) at load (bf16 segs only).
// STATS: per-column sum/sumsq of stored value -> stats[256] (double atomics).
// Block: 256 thr = 4 waves; wave computes 32 rows x 128 cols; 16x16x32 MFMA.
template<int K, int NSEG, int F32MASK, bool BIAS, bool TANH_ACT, bool ADDEND,
         bool BNIN, bool STATS, bool STOREF, bool STOREB>
__global__ __launch_bounds__(256) void mgemm(
    const void* __restrict__ A0, const void* __restrict__ A1, const void* __restrict__ A2,
    const __hip_bfloat16* __restrict__ Wt,   // [128][K]
    const float* __restrict__ bias,
    const float* __restrict__ addend,        // n x 128 f32
    const float* __restrict__ mu, const float* __restrict__ rstd,
    const float* __restrict__ gm, const float* __restrict__ bt,
    double* __restrict__ stats,
    float* __restrict__ outf, __hip_bfloat16* __restrict__ outb, int n)
{
    __shared__ float ssum[128];
    __shared__ float ssq[128];
    constexpr int SEGW = K / NSEG;
    const int tid  = threadIdx.x;
    const int lane = tid & 63;
    const int wid  = tid >> 6;
    const int l16  = lane & 15;
    const int lhi  = lane >> 4;                 // 0..3
    const int brow = blockIdx.x * 128 + wid * 32;

    if (STATS) {
        if (tid < 128) { ssum[tid] = 0.f; ssq[tid] = 0.f; }
        __syncthreads();
    }

    f32x4 acc[2][8];
#pragma unroll
    for (int t = 0; t < 2; ++t)
#pragma unroll
        for (int c = 0; c < 8; ++c)
#pragma unroll
            for (int i = 0; i < 4; ++i) acc[t][c][i] = 0.f;

    const void* seg[3] = {A0, A1, A2};

#pragma unroll
    for (int k0 = 0; k0 < K; k0 += 32) {
        const int si   = (NSEG == 1) ? 0 : (k0 >> 7);
        const int kloc = (NSEG == 1) ? k0 : (k0 & 127);
        bf16x8 afr[2];
#pragma unroll
        for (int t = 0; t < 2; ++t) {
            int row = brow + t * 16 + l16;
            if (row > n - 1) row = n - 1;
            if ((F32MASK >> si) & 1) {
                const float* p = (const float*)seg[si] + (size_t)row * SEGW + kloc + lhi * 8;
                float4 u0 = *reinterpret_cast<const float4*>(p);
                float4 u1 = *reinterpret_cast<const float4*>(p + 4);
                bf16x8 a;
                a[0] = (__bf16)u0.x; a[1] = (__bf16)u0.y; a[2] = (__bf16)u0.z; a[3] = (__bf16)u0.w;
                a[4] = (__bf16)u1.x; a[5] = (__bf16)u1.y; a[6] = (__bf16)u1.z; a[7] = (__bf16)u1.w;
                afr[t] = a;
            } else {
                const __hip_bfloat16* p = (const __hip_bfloat16*)seg[si] + (size_t)row * SEGW + kloc + lhi * 8;
                bf16x8 a = *reinterpret_cast<const bf16x8*>(p);
                if (BNIN) {
#pragma unroll
                    for (int j = 0; j < 8; ++j) {
                        int kk = kloc + lhi * 8 + j;
                        float f = (float)a[j];
                        f = fmaxf((f - mu[kk]) * rstd[kk] * gm[kk] + bt[kk], 0.f);
                        a[j] = (__bf16)f;
                    }
                }
                afr[t] = a;
            }
        }
#pragma unroll
        for (int c = 0; c < 8; ++c) {
            const __hip_bfloat16* wp = Wt + (size_t)(c * 16 + l16) * K + k0 + lhi * 8;
            bf16x8 b = *reinterpret_cast<const bf16x8*>(wp);
            acc[0][c] = __builtin_amdgcn_mfma_f32_16x16x32_bf16(afr[0], b, acc[0][c], 0, 0, 0);
            acc[1][c] = __builtin_amdgcn_mfma_f32_16x16x32_bf16(afr[1], b, acc[1][c], 0, 0, 0);
        }
    }

    // epilogue: lane holds rows lhi*4+r (within 16-tile), col = c*16+l16
#pragma unroll
    for (int t = 0; t < 2; ++t) {
#pragma unroll
        for (int c = 0; c < 8; ++c) {
            const int col = c * 16 + l16;
            const float bv = BIAS ? bias[col] : 0.f;
            float s = 0.f, q = 0.f;
#pragma unroll
            for (int r = 0; r < 4; ++r) {
                int grow = brow + t * 16 + lhi * 4 + r;
                bool ok = grow < n;
                float v = acc[t][c][r] + bv;
                if (ADDEND && ok) v += addend[(size_t)grow * 128 + col];
                if (TANH_ACT) v = fast_tanh(v);
                if (ok) {
                    if (STOREF) outf[(size_t)grow * 128 + col] = v;
                    if (STOREB) outb[(size_t)grow * 128 + col] = __float2bfloat16(v);
                    if (STATS) { s += v; q += v * v; }
                }
            }
            if (STATS) {
                atomicAdd(&ssum[col], s);
                atomicAdd(&ssq[col], q);
            }
        }
    }
    if (STATS) {
        __syncthreads();
        if (tid < 128) {
            atomicAdd(&stats[tid],       (double)ssum[tid]);
            atomicAdd(&stats[128 + tid], (double)ssq[tid]);
        }
    }
}

__global__ void bn_finalize(const double* __restrict__ stats,
                            float* __restrict__ mu, float* __restrict__ rstd, int n) {
    int c = threadIdx.x;
    if (c < 128) {
        double m = stats[c] / (double)n;
        double var = stats[128 + c] / (double)n - m * m;
        mu[c] = (float)m;
        rstd[c] = rsqrtf((float)var + 1e-5f);
    }
}

// prob = sigmoid( relu(BN(M2)) @ Wm3 + bm3 ) — one wave per row, bf16 M2
__global__ void gemv_prob(const __hip_bfloat16* __restrict__ M2,
                          const float* __restrict__ mu, const float* __restrict__ rstd,
                          const float* __restrict__ g, const float* __restrict__ be,
                          const float* __restrict__ Wm3, const float* __restrict__ bm3,
                          float* __restrict__ outp, int n) {
    int wid = (int)((blockIdx.x * (size_t)blockDim.x + threadIdx.x) >> 6);
    int lane = threadIdx.x & 63;
    if (wid >= n) return;
    float s = 0.f;
#pragma unroll
    for (int t = 0; t < 2; ++t) {
        int k = lane + t * 64;
        float a = __bfloat162float(M2[(size_t)wid * 128 + k]);
        a = fmaxf((a - mu[k]) * rstd[k] * g[k] + be[k], 0.f);
        s += a * Wm3[k];
    }
#pragma unroll
    for (int off = 32; off > 0; off >>= 1) s += __shfl_down(s, off);
    if (lane == 0) outp[wid] = 1.f / (1.f + __expf(-(s + bm3[0])));
}

extern "C" void kernel_launch(void* const* d_in, const int* in_sizes, int n_in,
                              void* d_out, int out_size, void* d_ws, size_t ws_size,
                              hipStream_t stream) {
    const float* x   = (const float*)d_in[0];
    const int*   pos = (const int*)d_in[1];
    const int*   neg = (const int*)d_in[2];
    const float* W_in = (const float*)d_in[3];
    const float* b_in = (const float*)d_in[4];
    const float* W1p = (const float*)d_in[5];
    const float* b1p = (const float*)d_in[6];
    const float* W1n = (const float*)d_in[7];
    const float* b1n = (const float*)d_in[8];
    const float* W2p = (const float*)d_in[9];
    const float* b2p = (const float*)d_in[10];
    const float* W2n = (const float*)d_in[11];
    const float* b2n = (const float*)d_in[12];
    const float* Wz  = (const float*)d_in[13];
    const float* bz  = (const float*)d_in[14];
    const float* Wm1 = (const float*)d_in[15];
    const float* bm1 = (const float*)d_in[16];
    const float* g1  = (const float*)d_in[17];
    const float* be1 = (const float*)d_in[18];
    const float* Wm2 = (const float*)d_in[19];
    const float* bm2 = (const float*)d_in[20];
    const float* g2  = (const float*)d_in[21];
    const float* be2 = (const float*)d_in[22];
    const float* Wm3 = (const float*)d_in[23];
    const float* bm3 = (const float*)d_in[24];

    char* ws = (char*)d_ws;
    size_t off = 0;
    auto carve = [&](size_t bytes) -> void* {
        void* p = (void*)(ws + off);
        off = (off + bytes + 255) & ~(size_t)255;
        return p;
    };
    const size_t NB  = (size_t)NN * 128 * sizeof(float);          // fp32 slot
    const size_t NBH = (size_t)NN * 128 * sizeof(__hip_bfloat16); // bf16 slot
    float* slot1 = (float*)carve(NB);   // aggC, then aggP
    float* slot2 = (float*)carve(NB);   // aggQ
    __hip_bfloat16* slotA = (__hip_bfloat16*)carve(NBH);  // hB
    __hip_bfloat16* slotB = (__hip_bfloat16*)carve(NBH);  // u1B -> z2B -> m2B
    __hip_bfloat16* slotC = (__hip_bfloat16*)carve(NBH);  // z1B -> m1B
    int*   cnt_p = (int*)carve(NN * sizeof(int));
    int*   cnt_n = (int*)carve(NN * sizeof(int));
    float* invp  = (float*)carve(NN * sizeof(float));
    float* invn  = (float*)carve(NN * sizeof(float));
    __hip_bfloat16* WtIn = (__hip_bfloat16*)carve(128 * 64 * 2);
    __hip_bfloat16* WtC1 = (__hip_bfloat16*)carve(128 * 128 * 2);
    __hip_bfloat16* WtL1 = (__hip_bfloat16*)carve(128 * 128 * 2);
    __hip_bfloat16* Wt2  = (__hip_bfloat16*)carve(128 * 384 * 2);
    __hip_bfloat16* WtZ  = (__hip_bfloat16*)carve(128 * 128 * 2);
    __hip_bfloat16* WtM1 = (__hip_bfloat16*)carve(128 * 128 * 2);
    __hip_bfloat16* WtM2 = (__hip_bfloat16*)carve(128 * 128 * 2);
    float* bcat1 = (float*)carve(128 * sizeof(float));
    float* b2cat = (float*)carve(128 * sizeof(float));
    double* stats1 = (double*)carve(256 * sizeof(double));
    double* stats2 = (double*)carve(256 * sizeof(double));
    float* mu1   = (float*)carve(128 * sizeof(float));
    float* rstd1 = (float*)carve(128 * sizeof(float));
    float* mu2   = (float*)carve(128 * sizeof(float));
    float* rstd2 = (float*)carve(128 * sizeof(float));
    (void)ws_size; (void)in_sizes; (void)n_in; (void)out_size;

    float* zout = (float*)d_out;                 // N x 128 (fp32)
    float* pout = zout + (size_t)NN * 128;       // N

    const int GB = (NN + 127) / 128;             // mgemm blocks (128 rows each)

    // init
    hipMemsetAsync(cnt_p, 0, NN * sizeof(int), stream);
    hipMemsetAsync(cnt_n, 0, NN * sizeof(int), stream);
    hipMemsetAsync(slot1, 0, NB, stream);        // aggC
    hipMemsetAsync(slot2, 0, NB, stream);        // aggQ
    hipMemsetAsync(stats1, 0, 256 * sizeof(double), stream);
    hipMemsetAsync(stats2, 0, 256 * sizeof(double), stream);
    count_kernel<<<(EP + 255) / 256, 256, 0, stream>>>(pos + EP, EP, cnt_p);
    count_kernel<<<(EN + 255) / 256, 256, 0, stream>>>(neg + EN, EN, cnt_n);
    inv_kernel<<<(NN + 255) / 256, 256, 0, stream>>>(cnt_p, cnt_n, invp, invn, NN);
    prep_weights<<<192, 256, 0, stream>>>(W_in, W1p, b1p, W1n, b1n, W2p, b2p, W2n, b2n,
                                          Wz, Wm1, Wm2,
                                          WtIn, WtC1, WtL1, Wt2, WtZ, WtM1, WtM2,
                                          bcat1, b2cat);

    // G1: h = x @ W_in + b_in -> hB (bf16). A fp32.
    mgemm<64, 1, 1, true, false, false, false, false, false, true><<<GB, 256, 0, stream>>>(
        x, nullptr, nullptr, WtIn, b_in, nullptr, nullptr, nullptr, nullptr, nullptr,
        nullptr, nullptr, slotA, NN);

    // G2: U1 = h @ Wcat1 -> u1B
    mgemm<128, 1, 0, false, false, false, false, false, false, true><<<GB, 256, 0, stream>>>(
        slotA, nullptr, nullptr, WtC1, nullptr, nullptr, nullptr, nullptr, nullptr, nullptr,
        nullptr, nullptr, slotB, NN);

    // aggC = [mean_pos(U1[:, :64]) | mean_neg(U1[:, 64:])]  (slot1)
    scatter_mean_bf16<6><<<(EP * 64 + 255) / 256, 256, 0, stream>>>(slotB, pos, pos + EP, EP, 0, invp, slot1, 0);
    scatter_mean_bf16<6><<<(EN * 64 + 255) / 256, 256, 0, stream>>>(slotB, neg, neg + EN, EN, 64, invn, slot1, 64);

    // G3: z1 = tanh(aggC + h @ Wloc1 + bcat1) -> z1B
    mgemm<128, 1, 0, true, true, true, false, false, false, true><<<GB, 256, 0, stream>>>(
        slotA, nullptr, nullptr, WtL1, bcat1, slot1, nullptr, nullptr, nullptr, nullptr,
        nullptr, nullptr, slotC, NN);

    // aggP = mean_pos(z1) (slot1, re-zeroed) ; aggQ = mean_neg(z1) (slot2)
    hipMemsetAsync(slot1, 0, NB, stream);
    scatter_mean_bf16<7><<<(EP * 128 + 255) / 256, 256, 0, stream>>>(slotC, pos, pos + EP, EP, 0, invp, slot1, 0);
    scatter_mean_bf16<7><<<(EN * 128 + 255) / 256, 256, 0, stream>>>(slotC, neg, neg + EN, EN, 0, invn, slot2, 0);

    // G4: z2 = tanh([P|Q|z1] @ W2cat + b2cat) -> z2B (slotB)
    mgemm<384, 3, 3, true, true, false, false, false, false, true><<<GB, 256, 0, stream>>>(
        slot1, slot2, slotC, Wt2, b2cat, nullptr, nullptr, nullptr, nullptr, nullptr,
        nullptr, nullptr, slotB, NN);

    // G5: z = tanh(z2 @ Wz + bz) -> zout (fp32 d_out)
    mgemm<128, 1, 0, true, true, false, false, false, true, false><<<GB, 256, 0, stream>>>(
        slotB, nullptr, nullptr, WtZ, bz, nullptr, nullptr, nullptr, nullptr, nullptr,
        nullptr, zout, nullptr, NN);

    // G6: M1 = z @ Wm1 + bm1 -> m1B (slotC) + stats1. A = zout fp32.
    mgemm<128, 1, 1, true, false, false, false, true, false, true><<<GB, 256, 0, stream>>>(
        zout, nullptr, nullptr, WtM1, bm1, nullptr, nullptr, nullptr, nullptr, nullptr,
        stats1, nullptr, slotC, NN);
    bn_finalize<<<1, 128, 0, stream>>>(stats1, mu1, rstd1, NN);

    // G7: M2 = relu(BN(M1)) @ Wm2 + bm2 -> m2B (slotB) + stats2
    mgemm<128, 1, 0, true, false, false, true, true, false, true><<<GB, 256, 0, stream>>>(
        slotC, nullptr, nullptr, WtM2, bm2, nullptr, mu1, rstd1, g1, be1,
        stats2, nullptr, slotB, NN);
    bn_finalize<<<1, 128, 0, stream>>>(stats2, mu2, rstd2, NN);

    // prob = sigmoid(relu(BN(M2)) @ Wm3 + bm3) -> d_out tail
    gemv_prob<<<(NN + 3) / 4, 256, 0, stream>>>(slotB, mu2, rstd2, g2, be2, Wm3, bm3, pout, NN);
}

// Round 3
// 850.535 us; speedup vs baseline: 1.3589x; 1.1711x over previous
//
#include <hip/hip_runtime.h>
#include <hip/hip_bf16.h>
#include <cstddef>
#include <cstdint>

#define NN 150000
#define EP 400000
#define EN 200000
#define SCAN_BS 256

typedef __bf16 bf16x8 __attribute__((ext_vector_type(8)));
typedef float  f32x4  __attribute__((ext_vector_type(4)));

__device__ __forceinline__ float fast_tanh(float x) {
    float e = __expf(2.f * x);
    return 1.f - 2.f / (e + 1.f);
}

// ---------------- counts ----------------
__global__ void count_kernel(const int* __restrict__ dst, int E, int* __restrict__ cnt) {
    int e = blockIdx.x * blockDim.x + threadIdx.x;
    if (e < E) atomicAdd(&cnt[dst[e]], 1);
}

// ---------------- exclusive scan (3-kernel) ----------------
__global__ void scan_block(const int* __restrict__ cnt, int n,
                           int* __restrict__ excl, int* __restrict__ bsum) {
    __shared__ int lds[SCAN_BS];
    int tid = threadIdx.x;
    int i = blockIdx.x * SCAN_BS + tid;
    int v = (i < n) ? cnt[i] : 0;
    lds[tid] = v;
    __syncthreads();
    for (int d = 1; d < SCAN_BS; d <<= 1) {
        int t = (tid >= d) ? lds[tid - d] : 0;
        __syncthreads();
        lds[tid] += t;
        __syncthreads();
    }
    if (i < n) excl[i] = lds[tid] - v;           // block-local exclusive
    if (tid == SCAN_BS - 1) bsum[blockIdx.x] = lds[tid];
}

__global__ void scan_bsum(int* __restrict__ bsum, int nb) {
    __shared__ int lds[SCAN_BS];
    __shared__ int carry;
    int tid = threadIdx.x;
    if (tid == 0) carry = 0;
    __syncthreads();
    for (int base = 0; base < nb; base += SCAN_BS) {
        int i = base + tid;
        int v = (i < nb) ? bsum[i] : 0;
        lds[tid] = v;
        __syncthreads();
        for (int d = 1; d < SCAN_BS; d <<= 1) {
            int t = (tid >= d) ? lds[tid - d] : 0;
            __syncthreads();
            lds[tid] += t;
            __syncthreads();
        }
        if (i < nb) bsum[i] = lds[tid] - v + carry;   // exclusive + carry
        __syncthreads();
        if (tid == 0) carry += lds[SCAN_BS - 1];
        __syncthreads();
    }
}

// excl[i] += bsum[block]; also writes cursor copy
__global__ void scan_add(const int* __restrict__ bsum, int n,
                         int* __restrict__ excl, int* __restrict__ cur) {
    int i = blockIdx.x * SCAN_BS + threadIdx.x;
    if (i < n) {
        int o = excl[i] + bsum[blockIdx.x];
        excl[i] = o;
        cur[i] = o;
    }
}

__global__ void fill_csr(const int* __restrict__ src, const int* __restrict__ dst, int E,
                         int* __restrict__ cur, int* __restrict__ csr) {
    int e = blockIdx.x * blockDim.x + threadIdx.x;
    if (e < E) {
        int d = dst[e];
        int p = atomicAdd(&cur[d], 1);
        csr[p] = src[e];
    }
}

// ---------------- CSR gather means ----------------
// round1: out[d][c<64] = mean_pos(U1[:, c]) ; out[d][c>=64] = mean_neg(U1[:, c])  (f32 out)
__global__ void gather_round1(const __hip_bfloat16* __restrict__ U1,
                              const int* __restrict__ offp, const int* __restrict__ cntp,
                              const int* __restrict__ csrp,
                              const int* __restrict__ offn, const int* __restrict__ cntn,
                              const int* __restrict__ csrn,
                              float* __restrict__ out) {
    int gid = blockIdx.x * blockDim.x + threadIdx.x;
    if (gid >= NN * 128) return;
    int d = gid >> 7, c = gid & 127;
    const int* off; const int* cnt; const int* csr;
    if (c < 64) { off = offp; cnt = cntp; csr = csrp; }
    else        { off = offn; cnt = cntn; csr = csrn; }
    int o = off[d], dg = cnt[d];
    float acc = 0.f;
    for (int e = 0; e < dg; ++e) {
        int s = csr[o + e];
        acc += __bfloat162float(U1[(size_t)s * 128 + c]);
    }
    out[(size_t)d * 128 + c] = acc / (float)(dg > 0 ? dg : 1);
}

// round2: P[d][:] = mean_pos(z1) ; Q[d][:] = mean_neg(z1)  (bf16 out)
__global__ void gather_round2(const __hip_bfloat16* __restrict__ z1,
                              const int* __restrict__ offp, const int* __restrict__ cntp,
                              const int* __restrict__ csrp,
                              const int* __restrict__ offn, const int* __restrict__ cntn,
                              const int* __restrict__ csrn,
                              __hip_bfloat16* __restrict__ P, __hip_bfloat16* __restrict__ Q) {
    int gid = blockIdx.x * blockDim.x + threadIdx.x;
    if (gid >= NN * 256) return;
    int d = gid >> 8, c = gid & 255;
    const int* off; const int* cnt; const int* csr; __hip_bfloat16* out;
    if (c < 128) { off = offp; cnt = cntp; csr = csrp; out = P; }
    else         { off = offn; cnt = cntn; csr = csrn; out = Q; c -= 128; }
    int o = off[d], dg = cnt[d];
    float acc = 0.f;
    for (int e = 0; e < dg; ++e) {
        int s = csr[o + e];
        acc += __bfloat162float(z1[(size_t)s * 128 + c]);
    }
    out[(size_t)d * 128 + c] = __float2bfloat16(acc / (float)(dg > 0 ? dg : 1));
}

// ---------------- weight prep: pack + transpose to [col][k] bf16 ----------------
__global__ void prep_weights(const float* __restrict__ W_in,
                             const float* __restrict__ W1p, const float* __restrict__ b1p,
                             const float* __restrict__ W1n, const float* __restrict__ b1n,
                             const float* __restrict__ W2p, const float* __restrict__ b2p,
                             const float* __restrict__ W2n, const float* __restrict__ b2n,
                             const float* __restrict__ Wz,  const float* __restrict__ Wm1,
                             const float* __restrict__ Wm2,
                             __hip_bfloat16* __restrict__ WtIn,  // [128][64]
                             __hip_bfloat16* __restrict__ WtC1,  // [128][128]
                             __hip_bfloat16* __restrict__ WtL1,  // [128][128]
                             __hip_bfloat16* __restrict__ Wt2,   // [128][384]
                             __hip_bfloat16* __restrict__ WtZ,
                             __hip_bfloat16* __restrict__ WtM1,
                             __hip_bfloat16* __restrict__ WtM2,
                             float* __restrict__ bcat1, float* __restrict__ b2cat) {
    int idx = blockIdx.x * blockDim.x + threadIdx.x;
    if (idx < 128 * 64) {
        int c = idx >> 6, k = idx & 63;
        WtIn[idx] = __float2bfloat16(W_in[k * 128 + c]);
    }
    if (idx < 128 * 128) {
        int c = idx >> 7, k = idx & 127;
        float v1 = (c < 64) ? W1p[k * 64 + c] : W1n[k * 64 + (c - 64)];
        WtC1[idx] = __float2bfloat16(v1);
        float v2 = (c < 64) ? W1p[(128 + k) * 64 + c] : W1n[(128 + k) * 64 + (c - 64)];
        WtL1[idx] = __float2bfloat16(v2);
        WtZ[idx]  = __float2bfloat16(Wz[k * 128 + c]);
        WtM1[idx] = __float2bfloat16(Wm1[k * 128 + c]);
        WtM2[idx] = __float2bfloat16(Wm2[k * 128 + c]);
    }
    if (idx < 128 * 384) {
        int c = idx / 384, r = idx % 384;
        float v = 0.f;
        if (r < 64)       { if (c < 64)  v = W2p[r * 64 + c]; }
        else if (r < 128) { if (c >= 64) v = W2n[(r - 64) * 64 + (c - 64)]; }
        else if (r < 192) { if (c >= 64) v = W2n[(64 + r - 128) * 64 + (c - 64)]; }
        else if (r < 256) { if (c < 64)  v = W2p[(64 + r - 192) * 64 + c]; }
        else if (r < 320) { if (c < 64)  v = W2p[(128 + r - 256) * 64 + c]; }
        else              { if (c >= 64) v = W2n[(128 + r - 320) * 64 + (c - 64)]; }
        Wt2[idx] = __float2bfloat16(v);
    }
    if (idx < 128) {
        bcat1[idx] = (idx < 64) ? b1p[idx] : b1n[idx - 64];
        b2cat[idx] = (idx < 64) ? b2p[idx] : b2n[idx - 64];
    }
}

// ---------------- bf16 MFMA GEMM, N=128 fixed ----------------
template<int K, int NSEG, int F32MASK, bool BIAS, bool TANH_ACT, bool ADDEND,
         bool BNIN, bool STATS, bool STOREF, bool STOREB>
__global__ __launch_bounds__(256) void mgemm(
    const void* __restrict__ A0, const void* __restrict__ A1, const void* __restrict__ A2,
    const __hip_bfloat16* __restrict__ Wt,   // [128][K]
    const float* __restrict__ bias,
    const float* __restrict__ addend,        // n x 128 f32
    const float* __restrict__ mu, const float* __restrict__ rstd,
    const float* __restrict__ gm, const float* __restrict__ bt,
    double* __restrict__ stats,
    float* __restrict__ outf, __hip_bfloat16* __restrict__ outb, int n)
{
    __shared__ float ssum[128];
    __shared__ float ssq[128];
    constexpr int SEGW = K / NSEG;
    const int tid  = threadIdx.x;
    const int lane = tid & 63;
    const int wid  = tid >> 6;
    const int l16  = lane & 15;
    const int lhi  = lane >> 4;                 // 0..3
    const int brow = blockIdx.x * 128 + wid * 32;

    if (STATS) {
        if (tid < 128) { ssum[tid] = 0.f; ssq[tid] = 0.f; }
        __syncthreads();
    }

    f32x4 acc[2][8];
#pragma unroll
    for (int t = 0; t < 2; ++t)
#pragma unroll
        for (int c = 0; c < 8; ++c)
#pragma unroll
            for (int i = 0; i < 4; ++i) acc[t][c][i] = 0.f;

    const void* seg[3] = {A0, A1, A2};

#pragma unroll
    for (int k0 = 0; k0 < K; k0 += 32) {
        const int si   = (NSEG == 1) ? 0 : (k0 >> 7);
        const int kloc = (NSEG == 1) ? k0 : (k0 & 127);
        bf16x8 afr[2];
#pragma unroll
        for (int t = 0; t < 2; ++t) {
            int row = brow + t * 16 + l16;
            if (row > n - 1) row = n - 1;
            if ((F32MASK >> si) & 1) {
                const float* p = (const float*)seg[si] + (size_t)row * SEGW + kloc + lhi * 8;
                float4 u0 = *reinterpret_cast<const float4*>(p);
                float4 u1 = *reinterpret_cast<const float4*>(p + 4);
                bf16x8 a;
                a[0] = (__bf16)u0.x; a[1] = (__bf16)u0.y; a[2] = (__bf16)u0.z; a[3] = (__bf16)u0.w;
                a[4] = (__bf16)u1.x; a[5] = (__bf16)u1.y; a[6] = (__bf16)u1.z; a[7] = (__bf16)u1.w;
                afr[t] = a;
            } else {
                const __hip_bfloat16* p = (const __hip_bfloat16*)seg[si] + (size_t)row * SEGW + kloc + lhi * 8;
                bf16x8 a = *reinterpret_cast<const bf16x8*>(p);
                if (BNIN) {
#pragma unroll
                    for (int j = 0; j < 8; ++j) {
                        int kk = kloc + lhi * 8 + j;
                        float f = (float)a[j];
                        f = fmaxf((f - mu[kk]) * rstd[kk] * gm[kk] + bt[kk], 0.f);
                        a[j] = (__bf16)f;
                    }
                }
                afr[t] = a;
            }
        }
#pragma unroll
        for (int c = 0; c < 8; ++c) {
            const __hip_bfloat16* wp = Wt + (size_t)(c * 16 + l16) * K + k0 + lhi * 8;
            bf16x8 b = *reinterpret_cast<const bf16x8*>(wp);
            acc[0][c] = __builtin_amdgcn_mfma_f32_16x16x32_bf16(afr[0], b, acc[0][c], 0, 0, 0);
            acc[1][c] = __builtin_amdgcn_mfma_f32_16x16x32_bf16(afr[1], b, acc[1][c], 0, 0, 0);
        }
    }

    // epilogue: lane holds rows lhi*4+r (within 16-tile), col = c*16+l16
#pragma unroll
    for (int t = 0; t < 2; ++t) {
#pragma unroll
        for (int c = 0; c < 8; ++c) {
            const int col = c * 16 + l16;
            const float bv = BIAS ? bias[col] : 0.f;
            float s = 0.f, q = 0.f;
#pragma unroll
            for (int r = 0; r < 4; ++r) {
                int grow = brow + t * 16 + lhi * 4 + r;
                bool ok = grow < n;
                float v = acc[t][c][r] + bv;
                if (ADDEND && ok) v += addend[(size_t)grow * 128 + col];
                if (TANH_ACT) v = fast_tanh(v);
                if (ok) {
                    if (STOREF) outf[(size_t)grow * 128 + col] = v;
                    if (STOREB) outb[(size_t)grow * 128 + col] = __float2bfloat16(v);
                    if (STATS) { s += v; q += v * v; }
                }
            }
            if (STATS) {
                atomicAdd(&ssum[col], s);
                atomicAdd(&ssq[col], q);
            }
        }
    }
    if (STATS) {
        __syncthreads();
        if (tid < 128) {
            atomicAdd(&stats[tid],       (double)ssum[tid]);
            atomicAdd(&stats[128 + tid], (double)ssq[tid]);
        }
    }
}

__global__ void bn_finalize(const double* __restrict__ stats,
                            float* __restrict__ mu, float* __restrict__ rstd, int n) {
    int c = threadIdx.x;
    if (c < 128) {
        double m = stats[c] / (double)n;
        double var = stats[128 + c] / (double)n - m * m;
        mu[c] = (float)m;
        rstd[c] = rsqrtf((float)var + 1e-5f);
    }
}

// prob = sigmoid( relu(BN(M2)) @ Wm3 + bm3 ) — one wave per row, bf16 M2
__global__ void gemv_prob(const __hip_bfloat16* __restrict__ M2,
                          const float* __restrict__ mu, const float* __restrict__ rstd,
                          const float* __restrict__ g, const float* __restrict__ be,
                          const float* __restrict__ Wm3, const float* __restrict__ bm3,
                          float* __restrict__ outp, int n) {
    int wid = (int)((blockIdx.x * (size_t)blockDim.x + threadIdx.x) >> 6);
    int lane = threadIdx.x & 63;
    if (wid >= n) return;
    float s = 0.f;
#pragma unroll
    for (int t = 0; t < 2; ++t) {
        int k = lane + t * 64;
        float a = __bfloat162float(M2[(size_t)wid * 128 + k]);
        a = fmaxf((a - mu[k]) * rstd[k] * g[k] + be[k], 0.f);
        s += a * Wm3[k];
    }
#pragma unroll
    for (int off = 32; off > 0; off >>= 1) s += __shfl_down(s, off);
    if (lane == 0) outp[wid] = 1.f / (1.f + __expf(-(s + bm3[0])));
}

extern "C" void kernel_launch(void* const* d_in, const int* in_sizes, int n_in,
                              void* d_out, int out_size, void* d_ws, size_t ws_size,
                              hipStream_t stream) {
    const float* x   = (const float*)d_in[0];
    const int*   pos = (const int*)d_in[1];
    const int*   neg = (const int*)d_in[2];
    const float* W_in = (const float*)d_in[3];
    const float* b_in = (const float*)d_in[4];
    const float* W1p = (const float*)d_in[5];
    const float* b1p = (const float*)d_in[6];
    const float* W1n = (const float*)d_in[7];
    const float* b1n = (const float*)d_in[8];
    const float* W2p = (const float*)d_in[9];
    const float* b2p = (const float*)d_in[10];
    const float* W2n = (const float*)d_in[11];
    const float* b2n = (const float*)d_in[12];
    const float* Wz  = (const float*)d_in[13];
    const float* bz  = (const float*)d_in[14];
    const float* Wm1 = (const float*)d_in[15];
    const float* bm1 = (const float*)d_in[16];
    const float* g1  = (const float*)d_in[17];
    const float* be1 = (const float*)d_in[18];
    const float* Wm2 = (const float*)d_in[19];
    const float* bm2 = (const float*)d_in[20];
    const float* g2  = (const float*)d_in[21];
    const float* be2 = (const float*)d_in[22];
    const float* Wm3 = (const float*)d_in[23];
    const float* bm3 = (const float*)d_in[24];

    char* ws = (char*)d_ws;
    size_t off = 0;
    auto carve = [&](size_t bytes) -> void* {
        void* p = (void*)(ws + off);
        off = (off + bytes + 255) & ~(size_t)255;
        return p;
    };
    const size_t NB  = (size_t)NN * 128 * sizeof(float);
    const size_t NBH = (size_t)NN * 128 * sizeof(__hip_bfloat16);
    float* slot1 = (float*)carve(NB);                     // aggC (f32); later aliased by P/Q bf16
    __hip_bfloat16* slotA = (__hip_bfloat16*)carve(NBH);  // hB
    __hip_bfloat16* slotB = (__hip_bfloat16*)carve(NBH);  // u1B -> z2B -> m1B
    __hip_bfloat16* slotC = (__hip_bfloat16*)carve(NBH);  // z1B -> zB -> m2B
    int* cnt_p = (int*)carve(NN * sizeof(int));
    int* cnt_n = (int*)carve(NN * sizeof(int));
    int* off_p = (int*)carve(NN * sizeof(int));
    int* off_n = (int*)carve(NN * sizeof(int));
    int* cur_p = (int*)carve(NN * sizeof(int));
    int* cur_n = (int*)carve(NN * sizeof(int));
    int* csr_p = (int*)carve(EP * sizeof(int));
    int* csr_n = (int*)carve(EN * sizeof(int));
    int* bsum_p = (int*)carve(1024 * sizeof(int));
    int* bsum_n = (int*)carve(1024 * sizeof(int));
    __hip_bfloat16* WtIn = (__hip_bfloat16*)carve(128 * 64 * 2);
    __hip_bfloat16* WtC1 = (__hip_bfloat16*)carve(128 * 128 * 2);
    __hip_bfloat16* WtL1 = (__hip_bfloat16*)carve(128 * 128 * 2);
    __hip_bfloat16* Wt2  = (__hip_bfloat16*)carve(128 * 384 * 2);
    __hip_bfloat16* WtZ  = (__hip_bfloat16*)carve(128 * 128 * 2);
    __hip_bfloat16* WtM1 = (__hip_bfloat16*)carve(128 * 128 * 2);
    __hip_bfloat16* WtM2 = (__hip_bfloat16*)carve(128 * 128 * 2);
    float* bcat1 = (float*)carve(128 * sizeof(float));
    float* b2cat = (float*)carve(128 * sizeof(float));
    double* stats1 = (double*)carve(256 * sizeof(double));
    double* stats2 = (double*)carve(256 * sizeof(double));
    float* mu1   = (float*)carve(128 * sizeof(float));
    float* rstd1 = (float*)carve(128 * sizeof(float));
    float* mu2   = (float*)carve(128 * sizeof(float));
    float* rstd2 = (float*)carve(128 * sizeof(float));
    (void)ws_size; (void)in_sizes; (void)n_in; (void)out_size;

    // P/Q bf16 alias slot1 (aggC dead after G3)
    __hip_bfloat16* aggPb = (__hip_bfloat16*)slot1;
    __hip_bfloat16* aggQb = aggPb + (size_t)NN * 128;

    float* zout = (float*)d_out;                 // N x 128 (fp32)
    float* pout = zout + (size_t)NN * 128;       // N

    const int GB = (NN + 127) / 128;
    const int NBLK = (NN + SCAN_BS - 1) / SCAN_BS;   // 586

    // ---- CSR build ----
    hipMemsetAsync(cnt_p, 0, NN * sizeof(int), stream);
    hipMemsetAsync(cnt_n, 0, NN * sizeof(int), stream);
    hipMemsetAsync(stats1, 0, 256 * sizeof(double), stream);
    hipMemsetAsync(stats2, 0, 256 * sizeof(double), stream);
    count_kernel<<<(EP + 255) / 256, 256, 0, stream>>>(pos + EP, EP, cnt_p);
    count_kernel<<<(EN + 255) / 256, 256, 0, stream>>>(neg + EN, EN, cnt_n);
    scan_block<<<NBLK, SCAN_BS, 0, stream>>>(cnt_p, NN, off_p, bsum_p);
    scan_block<<<NBLK, SCAN_BS, 0, stream>>>(cnt_n, NN, off_n, bsum_n);
    scan_bsum<<<1, SCAN_BS, 0, stream>>>(bsum_p, NBLK);
    scan_bsum<<<1, SCAN_BS, 0, stream>>>(bsum_n, NBLK);
    scan_add<<<NBLK, SCAN_BS, 0, stream>>>(bsum_p, NN, off_p, cur_p);
    scan_add<<<NBLK, SCAN_BS, 0, stream>>>(bsum_n, NN, off_n, cur_n);
    fill_csr<<<(EP + 255) / 256, 256, 0, stream>>>(pos, pos + EP, EP, cur_p, csr_p);
    fill_csr<<<(EN + 255) / 256, 256, 0, stream>>>(neg, neg + EN, EN, cur_n, csr_n);
    prep_weights<<<192, 256, 0, stream>>>(W_in, W1p, b1p, W1n, b1n, W2p, b2p, W2n, b2n,
                                          Wz, Wm1, Wm2,
                                          WtIn, WtC1, WtL1, Wt2, WtZ, WtM1, WtM2,
                                          bcat1, b2cat);

    // G1: h = x @ W_in + b_in -> hB
    mgemm<64, 1, 1, true, false, false, false, false, false, true><<<GB, 256, 0, stream>>>(
        x, nullptr, nullptr, WtIn, b_in, nullptr, nullptr, nullptr, nullptr, nullptr,
        nullptr, nullptr, slotA, NN);

    // G2: U1 = h @ Wcat1 -> u1B
    mgemm<128, 1, 0, false, false, false, false, false, false, true><<<GB, 256, 0, stream>>>(
        slotA, nullptr, nullptr, WtC1, nullptr, nullptr, nullptr, nullptr, nullptr, nullptr,
        nullptr, nullptr, slotB, NN);

    // aggC = [mean_pos(U1[:, :64]) | mean_neg(U1[:, 64:])] -> slot1 (f32)
    gather_round1<<<(NN * 128 + 255) / 256, 256, 0, stream>>>(
        slotB, off_p, cnt_p, csr_p, off_n, cnt_n, csr_n, slot1);

    // G3: z1 = tanh(aggC + h @ Wloc1 + bcat1) -> z1B (slotC)
    mgemm<128, 1, 0, true, true, true, false, false, false, true><<<GB, 256, 0, stream>>>(
        slotA, nullptr, nullptr, WtL1, bcat1, slot1, nullptr, nullptr, nullptr, nullptr,
        nullptr, nullptr, slotC, NN);

    // P = mean_pos(z1), Q = mean_neg(z1) -> bf16, alias slot1
    gather_round2<<<(NN * 256 + 255) / 256, 256, 0, stream>>>(
        slotC, off_p, cnt_p, csr_p, off_n, cnt_n, csr_n, aggPb, aggQb);

    // G4: z2 = tanh([P|Q|z1] @ W2cat + b2cat) -> z2B (slotB)
    mgemm<384, 3, 0, true, true, false, false, false, false, true><<<GB, 256, 0, stream>>>(
        aggPb, aggQb, slotC, Wt2, b2cat, nullptr, nullptr, nullptr, nullptr, nullptr,
        nullptr, nullptr, slotB, NN);

    // G5: z = tanh(z2 @ Wz + bz) -> zout (f32) + zB (slotC)
    mgemm<128, 1, 0, true, true, false, false, false, true, true><<<GB, 256, 0, stream>>>(
        slotB, nullptr, nullptr, WtZ, bz, nullptr, nullptr, nullptr, nullptr, nullptr,
        nullptr, zout, slotC, NN);

    // G6: M1 = z @ Wm1 + bm1 -> m1B (slotB) + stats1
    mgemm<128, 1, 0, true, false, false, false, true, false, true><<<GB, 256, 0, stream>>>(
        slotC, nullptr, nullptr, WtM1, bm1, nullptr, nullptr, nullptr, nullptr, nullptr,
        stats1, nullptr, slotB, NN);
    bn_finalize<<<1, 128, 0, stream>>>(stats1, mu1, rstd1, NN);

    // G7: M2 = relu(BN(M1)) @ Wm2 + bm2 -> m2B (slotC) + stats2
    mgemm<128, 1, 0, true, false, false, true, true, false, true><<<GB, 256, 0, stream>>>(
        slotB, nullptr, nullptr, WtM2, bm2, nullptr, mu1, rstd1, g1, be1,
        stats2, nullptr, slotC, NN);
    bn_finalize<<<1, 128, 0, stream>>>(stats2, mu2, rstd2, NN);

    // prob = sigmoid(relu(BN(M2)) @ Wm3 + bm3) -> d_out tail
    gemv_prob<<<(NN + 3) / 4, 256, 0, stream>>>(slotC, mu2, rstd2, g2, be2, Wm3, bm3, pout, NN);
}

// Round 4
// 655.216 us; speedup vs baseline: 1.7640x; 1.2981x over previous
//
#include <hip/hip_runtime.h>
#include <hip/hip_bf16.h>
#include <cstddef>
#include <cstdint>

#define NN 150000
#define EP 400000
#define EN 200000
#define SCAN_BS 256

typedef __bf16 bf16x8 __attribute__((ext_vector_type(8)));
typedef float  f32x4  __attribute__((ext_vector_type(4)));

__device__ __forceinline__ float fast_tanh(float x) {
    float e = __expf(2.f * x);
    return 1.f - 2.f / (e + 1.f);
}

// ---------------- counts ----------------
__global__ void count_kernel(const int* __restrict__ dst, int E, int* __restrict__ cnt) {
    int e = blockIdx.x * blockDim.x + threadIdx.x;
    if (e < E) atomicAdd(&cnt[dst[e]], 1);
}

// ---------------- exclusive scan (3-kernel) ----------------
__global__ void scan_block(const int* __restrict__ cnt, int n,
                           int* __restrict__ excl, int* __restrict__ bsum) {
    __shared__ int lds[SCAN_BS];
    int tid = threadIdx.x;
    int i = blockIdx.x * SCAN_BS + tid;
    int v = (i < n) ? cnt[i] : 0;
    lds[tid] = v;
    __syncthreads();
    for (int d = 1; d < SCAN_BS; d <<= 1) {
        int t = (tid >= d) ? lds[tid - d] : 0;
        __syncthreads();
        lds[tid] += t;
        __syncthreads();
    }
    if (i < n) excl[i] = lds[tid] - v;
    if (tid == SCAN_BS - 1) bsum[blockIdx.x] = lds[tid];
}

__global__ void scan_bsum(int* __restrict__ bsum, int nb) {
    __shared__ int lds[SCAN_BS];
    __shared__ int carry;
    int tid = threadIdx.x;
    if (tid == 0) carry = 0;
    __syncthreads();
    for (int base = 0; base < nb; base += SCAN_BS) {
        int i = base + tid;
        int v = (i < nb) ? bsum[i] : 0;
        lds[tid] = v;
        __syncthreads();
        for (int d = 1; d < SCAN_BS; d <<= 1) {
            int t = (tid >= d) ? lds[tid - d] : 0;
            __syncthreads();
            lds[tid] += t;
            __syncthreads();
        }
        if (i < nb) bsum[i] = lds[tid] - v + carry;
        __syncthreads();
        if (tid == 0) carry += lds[SCAN_BS - 1];
        __syncthreads();
    }
}

__global__ void scan_add(const int* __restrict__ bsum, int n,
                         int* __restrict__ excl, int* __restrict__ cur) {
    int i = blockIdx.x * SCAN_BS + threadIdx.x;
    if (i < n) {
        int o = excl[i] + bsum[blockIdx.x];
        excl[i] = o;
        cur[i] = o;
    }
}

__global__ void fill_csr(const int* __restrict__ src, const int* __restrict__ dst, int E,
                         int* __restrict__ cur, int* __restrict__ csr) {
    int e = blockIdx.x * blockDim.x + threadIdx.x;
    if (e < E) {
        int d = dst[e];
        int p = atomicAdd(&cur[d], 1);
        csr[p] = src[e];
    }
}

// ---------------- vectorized CSR gather means (bf16x8 per lane) ----------------
// round1: out[d][c<64] = mean_pos(U1[:, c]) ; out[d][c>=64] = mean_neg(U1[:, c])  (f32 out)
// thread = (node, 8-col group); 16 threads/node.
__global__ void gather1v(const __hip_bfloat16* __restrict__ U1,
                         const int* __restrict__ offp, const int* __restrict__ cntp,
                         const int* __restrict__ csrp,
                         const int* __restrict__ offn, const int* __restrict__ cntn,
                         const int* __restrict__ csrn,
                         float* __restrict__ out) {
    int gid = blockIdx.x * blockDim.x + threadIdx.x;
    if (gid >= NN * 16) return;
    int d = gid >> 4, cg = gid & 15;
    int c0 = cg * 8;
    const int* off; const int* cnt; const int* csr;
    if (cg < 8) { off = offp; cnt = cntp; csr = csrp; }
    else        { off = offn; cnt = cntn; csr = csrn; }
    int o = off[d], dg = cnt[d];
    float acc[8] = {0.f, 0.f, 0.f, 0.f, 0.f, 0.f, 0.f, 0.f};
    for (int e = 0; e < dg; ++e) {
        int s = csr[o + e];
        bf16x8 v = *reinterpret_cast<const bf16x8*>(&U1[(size_t)s * 128 + c0]);
#pragma unroll
        for (int j = 0; j < 8; ++j) acc[j] += (float)v[j];
    }
    float inv = 1.f / (float)(dg > 0 ? dg : 1);
    float4 o0 = make_float4(acc[0] * inv, acc[1] * inv, acc[2] * inv, acc[3] * inv);
    float4 o1 = make_float4(acc[4] * inv, acc[5] * inv, acc[6] * inv, acc[7] * inv);
    *reinterpret_cast<float4*>(&out[(size_t)d * 128 + c0 + 0]) = o0;
    *reinterpret_cast<float4*>(&out[(size_t)d * 128 + c0 + 4]) = o1;
}

// round2: P[d][:] = mean_pos(z1) ; Q[d][:] = mean_neg(z1)  (bf16 out)
// thread = (node, 8-col group of P or Q); 32 threads/node.
__global__ void gather2v(const __hip_bfloat16* __restrict__ z1,
                         const int* __restrict__ offp, const int* __restrict__ cntp,
                         const int* __restrict__ csrp,
                         const int* __restrict__ offn, const int* __restrict__ cntn,
                         const int* __restrict__ csrn,
                         __hip_bfloat16* __restrict__ P, __hip_bfloat16* __restrict__ Q) {
    int gid = blockIdx.x * blockDim.x + threadIdx.x;
    if (gid >= NN * 32) return;
    int d = gid >> 5, cg = gid & 31;
    const int* off; const int* cnt; const int* csr; __hip_bfloat16* out; int c0;
    if (cg < 16) { off = offp; cnt = cntp; csr = csrp; out = P; c0 = cg * 8; }
    else         { off = offn; cnt = cntn; csr = csrn; out = Q; c0 = (cg - 16) * 8; }
    int o = off[d], dg = cnt[d];
    float acc[8] = {0.f, 0.f, 0.f, 0.f, 0.f, 0.f, 0.f, 0.f};
    for (int e = 0; e < dg; ++e) {
        int s = csr[o + e];
        bf16x8 v = *reinterpret_cast<const bf16x8*>(&z1[(size_t)s * 128 + c0]);
#pragma unroll
        for (int j = 0; j < 8; ++j) acc[j] += (float)v[j];
    }
    float inv = 1.f / (float)(dg > 0 ? dg : 1);
    bf16x8 r;
#pragma unroll
    for (int j = 0; j < 8; ++j) r[j] = (__bf16)(acc[j] * inv);
    *reinterpret_cast<bf16x8*>(&out[(size_t)d * 128 + c0]) = r;
}

// ---------------- weight prep: pack + transpose to [col][k] bf16 ----------------
__global__ void prep_weights(const float* __restrict__ W_in,
                             const float* __restrict__ W1p, const float* __restrict__ b1p,
                             const float* __restrict__ W1n, const float* __restrict__ b1n,
                             const float* __restrict__ W2p, const float* __restrict__ b2p,
                             const float* __restrict__ W2n, const float* __restrict__ b2n,
                             const float* __restrict__ Wz,  const float* __restrict__ Wm1,
                             const float* __restrict__ Wm2,
                             __hip_bfloat16* __restrict__ WtIn,  // [128][64]
                             __hip_bfloat16* __restrict__ WtC1,  // [128][128]
                             __hip_bfloat16* __restrict__ WtL1,  // [128][128]
                             __hip_bfloat16* __restrict__ Wt2,   // [128][384]
                             __hip_bfloat16* __restrict__ WtZ,
                             __hip_bfloat16* __restrict__ WtM1,
                             __hip_bfloat16* __restrict__ WtM2,
                             float* __restrict__ bcat1, float* __restrict__ b2cat) {
    int idx = blockIdx.x * blockDim.x + threadIdx.x;
    if (idx < 128 * 64) {
        int c = idx >> 6, k = idx & 63;
        WtIn[idx] = __float2bfloat16(W_in[k * 128 + c]);
    }
    if (idx < 128 * 128) {
        int c = idx >> 7, k = idx & 127;
        float v1 = (c < 64) ? W1p[k * 64 + c] : W1n[k * 64 + (c - 64)];
        WtC1[idx] = __float2bfloat16(v1);
        float v2 = (c < 64) ? W1p[(128 + k) * 64 + c] : W1n[(128 + k) * 64 + (c - 64)];
        WtL1[idx] = __float2bfloat16(v2);
        WtZ[idx]  = __float2bfloat16(Wz[k * 128 + c]);
        WtM1[idx] = __float2bfloat16(Wm1[k * 128 + c]);
        WtM2[idx] = __float2bfloat16(Wm2[k * 128 + c]);
    }
    if (idx < 128 * 384) {
        int c = idx / 384, r = idx % 384;
        float v = 0.f;
        if (r < 64)       { if (c < 64)  v = W2p[r * 64 + c]; }
        else if (r < 128) { if (c >= 64) v = W2n[(r - 64) * 64 + (c - 64)]; }
        else if (r < 192) { if (c >= 64) v = W2n[(64 + r - 128) * 64 + (c - 64)]; }
        else if (r < 256) { if (c < 64)  v = W2p[(64 + r - 192) * 64 + c]; }
        else if (r < 320) { if (c < 64)  v = W2p[(128 + r - 256) * 64 + c]; }
        else              { if (c >= 64) v = W2n[(128 + r - 320) * 64 + (c - 64)]; }
        Wt2[idx] = __float2bfloat16(v);
    }
    if (idx < 128) {
        bcat1[idx] = (idx < 64) ? b1p[idx] : b1n[idx - 64];
        b2cat[idx] = (idx < 64) ? b2p[idx] : b2n[idx - 64];
    }
}

// ---------------- bf16 MFMA GEMM, N=128 fixed ----------------
template<int K, int NSEG, int F32MASK, bool BIAS, bool TANH_ACT, bool ADDEND,
         bool BNIN, bool STATS, bool STOREF, bool STOREB>
__global__ __launch_bounds__(256) void mgemm(
    const void* __restrict__ A0, const void* __restrict__ A1, const void* __restrict__ A2,
    const __hip_bfloat16* __restrict__ Wt,   // [128][K]
    const float* __restrict__ bias,
    const float* __restrict__ addend,        // n x 128 f32
    const float* __restrict__ mu, const float* __restrict__ rstd,
    const float* __restrict__ gm, const float* __restrict__ bt,
    double* __restrict__ stats,
    float* __restrict__ outf, __hip_bfloat16* __restrict__ outb, int n)
{
    __shared__ float ssum[128];
    __shared__ float ssq[128];
    constexpr int SEGW = K / NSEG;
    const int tid  = threadIdx.x;
    const int lane = tid & 63;
    const int wid  = tid >> 6;
    const int l16  = lane & 15;
    const int lhi  = lane >> 4;                 // 0..3
    const int brow = blockIdx.x * 128 + wid * 32;

    if (STATS) {
        if (tid < 128) { ssum[tid] = 0.f; ssq[tid] = 0.f; }
        __syncthreads();
    }

    f32x4 acc[2][8];
#pragma unroll
    for (int t = 0; t < 2; ++t)
#pragma unroll
        for (int c = 0; c < 8; ++c)
#pragma unroll
            for (int i = 0; i < 4; ++i) acc[t][c][i] = 0.f;

    const void* seg[3] = {A0, A1, A2};

#pragma unroll
    for (int k0 = 0; k0 < K; k0 += 32) {
        const int si   = (NSEG == 1) ? 0 : (k0 >> 7);
        const int kloc = (NSEG == 1) ? k0 : (k0 & 127);
        bf16x8 afr[2];
#pragma unroll
        for (int t = 0; t < 2; ++t) {
            int row = brow + t * 16 + l16;
            if (row > n - 1) row = n - 1;
            if ((F32MASK >> si) & 1) {
                const float* p = (const float*)seg[si] + (size_t)row * SEGW + kloc + lhi * 8;
                float4 u0 = *reinterpret_cast<const float4*>(p);
                float4 u1 = *reinterpret_cast<const float4*>(p + 4);
                bf16x8 a;
                a[0] = (__bf16)u0.x; a[1] = (__bf16)u0.y; a[2] = (__bf16)u0.z; a[3] = (__bf16)u0.w;
                a[4] = (__bf16)u1.x; a[5] = (__bf16)u1.y; a[6] = (__bf16)u1.z; a[7] = (__bf16)u1.w;
                afr[t] = a;
            } else {
                const __hip_bfloat16* p = (const __hip_bfloat16*)seg[si] + (size_t)row * SEGW + kloc + lhi * 8;
                bf16x8 a = *reinterpret_cast<const bf16x8*>(p);
                if (BNIN) {
#pragma unroll
                    for (int j = 0; j < 8; ++j) {
                        int kk = kloc + lhi * 8 + j;
                        float f = (float)a[j];
                        f = fmaxf((f - mu[kk]) * rstd[kk] * gm[kk] + bt[kk], 0.f);
                        a[j] = (__bf16)f;
                    }
                }
                afr[t] = a;
            }
        }
#pragma unroll
        for (int c = 0; c < 8; ++c) {
            const __hip_bfloat16* wp = Wt + (size_t)(c * 16 + l16) * K + k0 + lhi * 8;
            bf16x8 b = *reinterpret_cast<const bf16x8*>(wp);
            acc[0][c] = __builtin_amdgcn_mfma_f32_16x16x32_bf16(afr[0], b, acc[0][c], 0, 0, 0);
            acc[1][c] = __builtin_amdgcn_mfma_f32_16x16x32_bf16(afr[1], b, acc[1][c], 0, 0, 0);
        }
    }

    // epilogue: lane holds rows lhi*4+r (within 16-tile), col = c*16+l16
#pragma unroll
    for (int t = 0; t < 2; ++t) {
#pragma unroll
        for (int c = 0; c < 8; ++c) {
            const int col = c * 16 + l16;
            const float bv = BIAS ? bias[col] : 0.f;
            float s = 0.f, q = 0.f;
#pragma unroll
            for (int r = 0; r < 4; ++r) {
                int grow = brow + t * 16 + lhi * 4 + r;
                bool ok = grow < n;
                float v = acc[t][c][r] + bv;
                if (ADDEND && ok) v += addend[(size_t)grow * 128 + col];
                if (TANH_ACT) v = fast_tanh(v);
                if (ok) {
                    if (STOREF) outf[(size_t)grow * 128 + col] = v;
                    if (STOREB) outb[(size_t)grow * 128 + col] = __float2bfloat16(v);
                    if (STATS) { s += v; q += v * v; }
                }
            }
            if (STATS) {
                atomicAdd(&ssum[col], s);
                atomicAdd(&ssq[col], q);
            }
        }
    }
    if (STATS) {
        __syncthreads();
        if (tid < 128) {
            atomicAdd(&stats[tid],       (double)ssum[tid]);
            atomicAdd(&stats[128 + tid], (double)ssq[tid]);
        }
    }
}

__global__ void bn_finalize(const double* __restrict__ stats,
                            float* __restrict__ mu, float* __restrict__ rstd, int n) {
    int c = threadIdx.x;
    if (c < 128) {
        double m = stats[c] / (double)n;
        double var = stats[128 + c] / (double)n - m * m;
        mu[c] = (float)m;
        rstd[c] = rsqrtf((float)var + 1e-5f);
    }
}

// prob = sigmoid( relu(BN(M2)) @ Wm3 + bm3 ) — one wave per row, bf16 M2
__global__ void gemv_prob(const __hip_bfloat16* __restrict__ M2,
                          const float* __restrict__ mu, const float* __restrict__ rstd,
                          const float* __restrict__ g, const float* __restrict__ be,
                          const float* __restrict__ Wm3, const float* __restrict__ bm3,
                          float* __restrict__ outp, int n) {
    int wid = (int)((blockIdx.x * (size_t)blockDim.x + threadIdx.x) >> 6);
    int lane = threadIdx.x & 63;
    if (wid >= n) return;
    float s = 0.f;
#pragma unroll
    for (int t = 0; t < 2; ++t) {
        int k = lane + t * 64;
        float a = __bfloat162float(M2[(size_t)wid * 128 + k]);
        a = fmaxf((a - mu[k]) * rstd[k] * g[k] + be[k], 0.f);
        s += a * Wm3[k];
    }
#pragma unroll
    for (int off = 32; off > 0; off >>= 1) s += __shfl_down(s, off);
    if (lane == 0) outp[wid] = 1.f / (1.f + __expf(-(s + bm3[0])));
}

extern "C" void kernel_launch(void* const* d_in, const int* in_sizes, int n_in,
                              void* d_out, int out_size, void* d_ws, size_t ws_size,
                              hipStream_t stream) {
    const float* x   = (const float*)d_in[0];
    const int*   pos = (const int*)d_in[1];
    const int*   neg = (const int*)d_in[2];
    const float* W_in = (const float*)d_in[3];
    const float* b_in = (const float*)d_in[4];
    const float* W1p = (const float*)d_in[5];
    const float* b1p = (const float*)d_in[6];
    const float* W1n = (const float*)d_in[7];
    const float* b1n = (const float*)d_in[8];
    const float* W2p = (const float*)d_in[9];
    const float* b2p = (const float*)d_in[10];
    const float* W2n = (const float*)d_in[11];
    const float* b2n = (const float*)d_in[12];
    const float* Wz  = (const float*)d_in[13];
    const float* bz  = (const float*)d_in[14];
    const float* Wm1 = (const float*)d_in[15];
    const float* bm1 = (const float*)d_in[16];
    const float* g1  = (const float*)d_in[17];
    const float* be1 = (const float*)d_in[18];
    const float* Wm2 = (const float*)d_in[19];
    const float* bm2 = (const float*)d_in[20];
    const float* g2  = (const float*)d_in[21];
    const float* be2 = (const float*)d_in[22];
    const float* Wm3 = (const float*)d_in[23];
    const float* bm3 = (const float*)d_in[24];

    char* ws = (char*)d_ws;
    size_t off = 0;
    auto carve = [&](size_t bytes) -> void* {
        void* p = (void*)(ws + off);
        off = (off + bytes + 255) & ~(size_t)255;
        return p;
    };
    const size_t NB  = (size_t)NN * 128 * sizeof(float);
    const size_t NBH = (size_t)NN * 128 * sizeof(__hip_bfloat16);
    float* slot1 = (float*)carve(NB);                     // aggC (f32); later aliased by P/Q bf16
    __hip_bfloat16* slotA = (__hip_bfloat16*)carve(NBH);  // hB
    __hip_bfloat16* slotB = (__hip_bfloat16*)carve(NBH);  // u1B -> z2B -> m1B
    __hip_bfloat16* slotC = (__hip_bfloat16*)carve(NBH);  // z1B -> zB -> m2B
    int* cnt_p = (int*)carve(NN * sizeof(int));
    int* cnt_n = (int*)carve(NN * sizeof(int));
    int* off_p = (int*)carve(NN * sizeof(int));
    int* off_n = (int*)carve(NN * sizeof(int));
    int* cur_p = (int*)carve(NN * sizeof(int));
    int* cur_n = (int*)carve(NN * sizeof(int));
    int* csr_p = (int*)carve(EP * sizeof(int));
    int* csr_n = (int*)carve(EN * sizeof(int));
    int* bsum_p = (int*)carve(1024 * sizeof(int));
    int* bsum_n = (int*)carve(1024 * sizeof(int));
    __hip_bfloat16* WtIn = (__hip_bfloat16*)carve(128 * 64 * 2);
    __hip_bfloat16* WtC1 = (__hip_bfloat16*)carve(128 * 128 * 2);
    __hip_bfloat16* WtL1 = (__hip_bfloat16*)carve(128 * 128 * 2);
    __hip_bfloat16* Wt2  = (__hip_bfloat16*)carve(128 * 384 * 2);
    __hip_bfloat16* WtZ  = (__hip_bfloat16*)carve(128 * 128 * 2);
    __hip_bfloat16* WtM1 = (__hip_bfloat16*)carve(128 * 128 * 2);
    __hip_bfloat16* WtM2 = (__hip_bfloat16*)carve(128 * 128 * 2);
    float* bcat1 = (float*)carve(128 * sizeof(float));
    float* b2cat = (float*)carve(128 * sizeof(float));
    double* stats1 = (double*)carve(256 * sizeof(double));
    double* stats2 = (double*)carve(256 * sizeof(double));
    float* mu1   = (float*)carve(128 * sizeof(float));
    float* rstd1 = (float*)carve(128 * sizeof(float));
    float* mu2   = (float*)carve(128 * sizeof(float));
    float* rstd2 = (float*)carve(128 * sizeof(float));
    (void)ws_size; (void)in_sizes; (void)n_in; (void)out_size;

    // P/Q bf16 alias slot1 (aggC dead after G3)
    __hip_bfloat16* aggPb = (__hip_bfloat16*)slot1;
    __hip_bfloat16* aggQb = aggPb + (size_t)NN * 128;

    float* zout = (float*)d_out;                 // N x 128 (fp32)
    float* pout = zout + (size_t)NN * 128;       // N

    const int GB = (NN + 127) / 128;
    const int NBLK = (NN + SCAN_BS - 1) / SCAN_BS;   // 586

    // ---- CSR build ----
    hipMemsetAsync(cnt_p, 0, NN * sizeof(int), stream);
    hipMemsetAsync(cnt_n, 0, NN * sizeof(int), stream);
    hipMemsetAsync(stats1, 0, 256 * sizeof(double), stream);
    hipMemsetAsync(stats2, 0, 256 * sizeof(double), stream);
    count_kernel<<<(EP + 255) / 256, 256, 0, stream>>>(pos + EP, EP, cnt_p);
    count_kernel<<<(EN + 255) / 256, 256, 0, stream>>>(neg + EN, EN, cnt_n);
    scan_block<<<NBLK, SCAN_BS, 0, stream>>>(cnt_p, NN, off_p, bsum_p);
    scan_block<<<NBLK, SCAN_BS, 0, stream>>>(cnt_n, NN, off_n, bsum_n);
    scan_bsum<<<1, SCAN_BS, 0, stream>>>(bsum_p, NBLK);
    scan_bsum<<<1, SCAN_BS, 0, stream>>>(bsum_n, NBLK);
    scan_add<<<NBLK, SCAN_BS, 0, stream>>>(bsum_p, NN, off_p, cur_p);
    scan_add<<<NBLK, SCAN_BS, 0, stream>>>(bsum_n, NN, off_n, cur_n);
    fill_csr<<<(EP + 255) / 256, 256, 0, stream>>>(pos, pos + EP, EP, cur_p, csr_p);
    fill_csr<<<(EN + 255) / 256, 256, 0, stream>>>(neg, neg + EN, EN, cur_n, csr_n);
    prep_weights<<<192, 256, 0, stream>>>(W_in, W1p, b1p, W1n, b1n, W2p, b2p, W2n, b2n,
                                          Wz, Wm1, Wm2,
                                          WtIn, WtC1, WtL1, Wt2, WtZ, WtM1, WtM2,
                                          bcat1, b2cat);

    // G1: h = x @ W_in + b_in -> hB
    mgemm<64, 1, 1, true, false, false, false, false, false, true><<<GB, 256, 0, stream>>>(
        x, nullptr, nullptr, WtIn, b_in, nullptr, nullptr, nullptr, nullptr, nullptr,
        nullptr, nullptr, slotA, NN);

    // G2: U1 = h @ Wcat1 -> u1B
    mgemm<128, 1, 0, false, false, false, false, false, false, true><<<GB, 256, 0, stream>>>(
        slotA, nullptr, nullptr, WtC1, nullptr, nullptr, nullptr, nullptr, nullptr, nullptr,
        nullptr, nullptr, slotB, NN);

    // aggC = [mean_pos(U1[:, :64]) | mean_neg(U1[:, 64:])] -> slot1 (f32)
    gather1v<<<(NN * 16 + 255) / 256, 256, 0, stream>>>(
        slotB, off_p, cnt_p, csr_p, off_n, cnt_n, csr_n, slot1);

    // G3: z1 = tanh(aggC + h @ Wloc1 + bcat1) -> z1B (slotC)
    mgemm<128, 1, 0, true, true, true, false, false, false, true><<<GB, 256, 0, stream>>>(
        slotA, nullptr, nullptr, WtL1, bcat1, slot1, nullptr, nullptr, nullptr, nullptr,
        nullptr, nullptr, slotC, NN);

    // P = mean_pos(z1), Q = mean_neg(z1) -> bf16, alias slot1
    gather2v<<<(NN * 32 + 255) / 256, 256, 0, stream>>>(
        slotC, off_p, cnt_p, csr_p, off_n, cnt_n, csr_n, aggPb, aggQb);

    // G4: z2 = tanh([P|Q|z1] @ W2cat + b2cat) -> z2B (slotB)
    mgemm<384, 3, 0, true, true, false, false, false, false, true><<<GB, 256, 0, stream>>>(
        aggPb, aggQb, slotC, Wt2, b2cat, nullptr, nullptr, nullptr, nullptr, nullptr,
        nullptr, nullptr, slotB, NN);

    // G5: z = tanh(z2 @ Wz + bz) -> zout (f32) + zB (slotC)
    mgemm<128, 1, 0, true, true, false, false, false, true, true><<<GB, 256, 0, stream>>>(
        slotB, nullptr, nullptr, WtZ, bz, nullptr, nullptr, nullptr, nullptr, nullptr,
        nullptr, zout, slotC, NN);

    // G6: M1 = z @ Wm1 + bm1 -> m1B (slotB) + stats1
    mgemm<128, 1, 0, true, false, false, false, true, false, true><<<GB, 256, 0, stream>>>(
        slotC, nullptr, nullptr, WtM1, bm1, nullptr, nullptr, nullptr, nullptr, nullptr,
        stats1, nullptr, slotB, NN);
    bn_finalize<<<1, 128, 0, stream>>>(stats1, mu1, rstd1, NN);

    // G7: M2 = relu(BN(M1)) @ Wm2 + bm2 -> m2B (slotC) + stats2
    mgemm<128, 1, 0, true, false, false, true, true, false, true><<<GB, 256, 0, stream>>>(
        slotB, nullptr, nullptr, WtM2, bm2, nullptr, mu1, rstd1, g1, be1,
        stats2, nullptr, slotC, NN);
    bn_finalize<<<1, 128, 0, stream>>>(stats2, mu2, rstd2, NN);

    // prob = sigmoid(relu(BN(M2)) @ Wm3 + bm3) -> d_out tail
    gemv_prob<<<(NN + 3) / 4, 256, 0, stream>>>(slotC, mu2, rstd2, g2, be2, Wm3, bm3, pout, NN);
}

// Round 5
// 652.631 us; speedup vs baseline: 1.7710x; 1.0040x over previous
//
#include <hip/hip_runtime.h>
#include <hip/hip_bf16.h>
#include <cstddef>
#include <cstdint>

#define NN 150000
#define EP 400000
#define EN 200000
#define SCAN_BS 256

typedef __bf16 bf16x8 __attribute__((ext_vector_type(8)));
typedef float  f32x4  __attribute__((ext_vector_type(4)));

__device__ __forceinline__ float fast_tanh(float x) {
    float e = __expf(2.f * x);
    return 1.f - 2.f / (e + 1.f);
}

// ---------------- counts ----------------
__global__ void count_kernel(const int* __restrict__ dst, int E, int* __restrict__ cnt) {
    int e = blockIdx.x * blockDim.x + threadIdx.x;
    if (e < E) atomicAdd(&cnt[dst[e]], 1);
}

// ---------------- exclusive scan (3-kernel) ----------------
__global__ void scan_block(const int* __restrict__ cnt, int n,
                           int* __restrict__ excl, int* __restrict__ bsum) {
    __shared__ int lds[SCAN_BS];
    int tid = threadIdx.x;
    int i = blockIdx.x * SCAN_BS + tid;
    int v = (i < n) ? cnt[i] : 0;
    lds[tid] = v;
    __syncthreads();
    for (int d = 1; d < SCAN_BS; d <<= 1) {
        int t = (tid >= d) ? lds[tid - d] : 0;
        __syncthreads();
        lds[tid] += t;
        __syncthreads();
    }
    if (i < n) excl[i] = lds[tid] - v;
    if (tid == SCAN_BS - 1) bsum[blockIdx.x] = lds[tid];
}

__global__ void scan_bsum(int* __restrict__ bsum, int nb) {
    __shared__ int lds[SCAN_BS];
    __shared__ int carry;
    int tid = threadIdx.x;
    if (tid == 0) carry = 0;
    __syncthreads();
    for (int base = 0; base < nb; base += SCAN_BS) {
        int i = base + tid;
        int v = (i < nb) ? bsum[i] : 0;
        lds[tid] = v;
        __syncthreads();
        for (int d = 1; d < SCAN_BS; d <<= 1) {
            int t = (tid >= d) ? lds[tid - d] : 0;
            __syncthreads();
            lds[tid] += t;
            __syncthreads();
        }
        if (i < nb) bsum[i] = lds[tid] - v + carry;
        __syncthreads();
        if (tid == 0) carry += lds[SCAN_BS - 1];
        __syncthreads();
    }
}

__global__ void scan_add(const int* __restrict__ bsum, int n,
                         int* __restrict__ excl, int* __restrict__ cur) {
    int i = blockIdx.x * SCAN_BS + threadIdx.x;
    if (i < n) {
        int o = excl[i] + bsum[blockIdx.x];
        excl[i] = o;
        cur[i] = o;
    }
}

__global__ void fill_csr(const int* __restrict__ src, const int* __restrict__ dst, int E,
                         int* __restrict__ cur, int* __restrict__ csr) {
    int e = blockIdx.x * blockDim.x + threadIdx.x;
    if (e < E) {
        int d = dst[e];
        int p = atomicAdd(&cur[d], 1);
        csr[p] = src[e];
    }
}

// ---------------- vectorized CSR gather means (bf16x8 per lane) ----------------
__global__ void gather1v(const __hip_bfloat16* __restrict__ U1,
                         const int* __restrict__ offp, const int* __restrict__ cntp,
                         const int* __restrict__ csrp,
                         const int* __restrict__ offn, const int* __restrict__ cntn,
                         const int* __restrict__ csrn,
                         float* __restrict__ out) {
    int gid = blockIdx.x * blockDim.x + threadIdx.x;
    if (gid >= NN * 16) return;
    int d = gid >> 4, cg = gid & 15;
    int c0 = cg * 8;
    const int* off; const int* cnt; const int* csr;
    if (cg < 8) { off = offp; cnt = cntp; csr = csrp; }
    else        { off = offn; cnt = cntn; csr = csrn; }
    int o = off[d], dg = cnt[d];
    float acc[8] = {0.f, 0.f, 0.f, 0.f, 0.f, 0.f, 0.f, 0.f};
    for (int e = 0; e < dg; ++e) {
        int s = csr[o + e];
        bf16x8 v = *reinterpret_cast<const bf16x8*>(&U1[(size_t)s * 128 + c0]);
#pragma unroll
        for (int j = 0; j < 8; ++j) acc[j] += (float)v[j];
    }
    float inv = 1.f / (float)(dg > 0 ? dg : 1);
    float4 o0 = make_float4(acc[0] * inv, acc[1] * inv, acc[2] * inv, acc[3] * inv);
    float4 o1 = make_float4(acc[4] * inv, acc[5] * inv, acc[6] * inv, acc[7] * inv);
    *reinterpret_cast<float4*>(&out[(size_t)d * 128 + c0 + 0]) = o0;
    *reinterpret_cast<float4*>(&out[(size_t)d * 128 + c0 + 4]) = o1;
}

__global__ void gather2v(const __hip_bfloat16* __restrict__ z1,
                         const int* __restrict__ offp, const int* __restrict__ cntp,
                         const int* __restrict__ csrp,
                         const int* __restrict__ offn, const int* __restrict__ cntn,
                         const int* __restrict__ csrn,
                         __hip_bfloat16* __restrict__ P, __hip_bfloat16* __restrict__ Q) {
    int gid = blockIdx.x * blockDim.x + threadIdx.x;
    if (gid >= NN * 32) return;
    int d = gid >> 5, cg = gid & 31;
    const int* off; const int* cnt; const int* csr; __hip_bfloat16* out; int c0;
    if (cg < 16) { off = offp; cnt = cntp; csr = csrp; out = P; c0 = cg * 8; }
    else         { off = offn; cnt = cntn; csr = csrn; out = Q; c0 = (cg - 16) * 8; }
    int o = off[d], dg = cnt[d];
    float acc[8] = {0.f, 0.f, 0.f, 0.f, 0.f, 0.f, 0.f, 0.f};
    for (int e = 0; e < dg; ++e) {
        int s = csr[o + e];
        bf16x8 v = *reinterpret_cast<const bf16x8*>(&z1[(size_t)s * 128 + c0]);
#pragma unroll
        for (int j = 0; j < 8; ++j) acc[j] += (float)v[j];
    }
    float inv = 1.f / (float)(dg > 0 ? dg : 1);
    bf16x8 r;
#pragma unroll
    for (int j = 0; j < 8; ++j) r[j] = (__bf16)(acc[j] * inv);
    *reinterpret_cast<bf16x8*>(&out[(size_t)d * 128 + c0]) = r;
}

// ---------------- weight prep ----------------
__global__ void prep_weights(const float* __restrict__ W_in,
                             const float* __restrict__ W1p, const float* __restrict__ b1p,
                             const float* __restrict__ W1n, const float* __restrict__ b1n,
                             const float* __restrict__ W2p, const float* __restrict__ b2p,
                             const float* __restrict__ W2n, const float* __restrict__ b2n,
                             const float* __restrict__ Wz,  const float* __restrict__ Wm1,
                             const float* __restrict__ Wm2,
                             __hip_bfloat16* __restrict__ WtIn,  // [128][64]
                             __hip_bfloat16* __restrict__ WtC1,  // [128][128]
                             __hip_bfloat16* __restrict__ WtL1,  // [128][128]
                             __hip_bfloat16* __restrict__ Wt2,   // [128][384]
                             __hip_bfloat16* __restrict__ WtZ,
                             __hip_bfloat16* __restrict__ WtM1,
                             __hip_bfloat16* __restrict__ WtM2,
                             float* __restrict__ bcat1, float* __restrict__ b2cat) {
    int idx = blockIdx.x * blockDim.x + threadIdx.x;
    if (idx < 128 * 64) {
        int c = idx >> 6, k = idx & 63;
        WtIn[idx] = __float2bfloat16(W_in[k * 128 + c]);
    }
    if (idx < 128 * 128) {
        int c = idx >> 7, k = idx & 127;
        float v1 = (c < 64) ? W1p[k * 64 + c] : W1n[k * 64 + (c - 64)];
        WtC1[idx] = __float2bfloat16(v1);
        float v2 = (c < 64) ? W1p[(128 + k) * 64 + c] : W1n[(128 + k) * 64 + (c - 64)];
        WtL1[idx] = __float2bfloat16(v2);
        WtZ[idx]  = __float2bfloat16(Wz[k * 128 + c]);
        WtM1[idx] = __float2bfloat16(Wm1[k * 128 + c]);
        WtM2[idx] = __float2bfloat16(Wm2[k * 128 + c]);
    }
    if (idx < 128 * 384) {
        int c = idx / 384, r = idx % 384;
        float v = 0.f;
        if (r < 64)       { if (c < 64)  v = W2p[r * 64 + c]; }
        else if (r < 128) { if (c >= 64) v = W2n[(r - 64) * 64 + (c - 64)]; }
        else if (r < 192) { if (c >= 64) v = W2n[(64 + r - 128) * 64 + (c - 64)]; }
        else if (r < 256) { if (c < 64)  v = W2p[(64 + r - 192) * 64 + c]; }
        else if (r < 320) { if (c < 64)  v = W2p[(128 + r - 256) * 64 + c]; }
        else              { if (c >= 64) v = W2n[(128 + r - 320) * 64 + (c - 64)]; }
        Wt2[idx] = __float2bfloat16(v);
    }
    if (idx < 128) {
        bcat1[idx] = (idx < 64) ? b1p[idx] : b1n[idx - 64];
        b2cat[idx] = (idx < 64) ? b2p[idx] : b2n[idx - 64];
    }
}

// ================= MFMA GEMM building blocks =================
// Wave = 32 rows x 128 cols. lane: l16 = lane&15, lhi = lane>>4.
// A-frag: lane holds A[row = t*16+l16][k = kk*32 + lhi*8 + j].
// C/D:    lane holds D[row = t*16+lhi*4+r][col = c*16+l16].

// swizzled per-wave LDS tile: [32 rows][256 B], XOR bits 4-6 by row&7
__device__ __forceinline__ int lds_off(int row, int b) {
    return row * 256 + (b ^ ((row & 7) << 4));
}

// MFMA over a 128-wide K chunk. KSTRIDE = row length of Wt.
template<int KSTRIDE>
__device__ __forceinline__ void mm128(const bf16x8 afr[4][2],
        const __hip_bfloat16* __restrict__ Wt, int k0, int l16, int lhi, f32x4 acc[2][8]) {
#pragma unroll
    for (int kk = 0; kk < 4; ++kk)
#pragma unroll
        for (int c = 0; c < 8; ++c) {
            bf16x8 b = *reinterpret_cast<const bf16x8*>(
                Wt + (size_t)(c * 16 + l16) * KSTRIDE + k0 + kk * 32 + lhi * 8);
            acc[0][c] = __builtin_amdgcn_mfma_f32_16x16x32_bf16(afr[kk][0], b, acc[0][c], 0, 0, 0);
            acc[1][c] = __builtin_amdgcn_mfma_f32_16x16x32_bf16(afr[kk][1], b, acc[1][c], 0, 0, 0);
        }
}

// hoisted global A-frag load, bf16, row stride 128, optional BN+relu
template<bool BNIN>
__device__ __forceinline__ void lda_g(const __hip_bfloat16* __restrict__ A,
        int brow, int l16, int lhi,
        const float* __restrict__ scale, const float* __restrict__ shift,
        int n, bf16x8 afr[4][2]) {
#pragma unroll
    for (int kk = 0; kk < 4; ++kk)
#pragma unroll
        for (int t = 0; t < 2; ++t) {
            int row = brow + t * 16 + l16; if (row > n - 1) row = n - 1;
            bf16x8 a = *reinterpret_cast<const bf16x8*>(A + (size_t)row * 128 + kk * 32 + lhi * 8);
            if (BNIN) {
#pragma unroll
                for (int j = 0; j < 8; ++j) {
                    int k = kk * 32 + lhi * 8 + j;
                    a[j] = (__bf16)fmaxf((float)a[j] * scale[k] + shift[k], 0.f);
                }
            }
            afr[kk][t] = a;
        }
}

// hoisted LDS A-frag load (per-wave swizzled tile)
__device__ __forceinline__ void lda_lds(const char* __restrict__ base, int l16, int lhi,
                                        bf16x8 afr[4][2]) {
#pragma unroll
    for (int kk = 0; kk < 4; ++kk)
#pragma unroll
        for (int t = 0; t < 2; ++t) {
            int row = t * 16 + l16;
            afr[kk][t] = *reinterpret_cast<const bf16x8*>(base + lds_off(row, kk * 64 + lhi * 16));
        }
}

// epilogue: bias/addend/tanh, stores, stats, optional LDS bf16 write
template<bool BIAS, bool TANH_ACT, bool ADDEND, bool STATS, bool STOREF, bool STOREB, bool TOLDS>
__device__ __forceinline__ void epi(f32x4 acc[2][8], int brow, int l16, int lhi,
        const float* __restrict__ bias, const float* __restrict__ addend,
        float* __restrict__ ssum, float* __restrict__ ssq,
        float* __restrict__ outf, __hip_bfloat16* __restrict__ outb,
        char* __restrict__ ldsbase, int n) {
#pragma unroll
    for (int t = 0; t < 2; ++t)
#pragma unroll
        for (int c = 0; c < 8; ++c) {
            const int col = c * 16 + l16;
            const float bv = BIAS ? bias[col] : 0.f;
            float s = 0.f, q = 0.f;
#pragma unroll
            for (int r = 0; r < 4; ++r) {
                int rl = t * 16 + lhi * 4 + r;
                int grow = brow + rl;
                bool ok = grow < n;
                float v = acc[t][c][r] + bv;
                if (ADDEND) { if (ok) v += addend[(size_t)grow * 128 + col]; }
                if (TANH_ACT) v = fast_tanh(v);
                if (TOLDS)
                    *reinterpret_cast<__hip_bfloat16*>(ldsbase + lds_off(rl, col * 2)) =
                        __float2bfloat16(v);
                if (ok) {
                    if (STOREF) outf[(size_t)grow * 128 + col] = v;
                    if (STOREB) outb[(size_t)grow * 128 + col] = __float2bfloat16(v);
                    if (STATS) { s += v; q += v * v; }
                }
            }
            if (STATS) { atomicAdd(&ssum[col], s); atomicAdd(&ssq[col], q); }
        }
}

__device__ __forceinline__ void zero_acc(f32x4 acc[2][8]) {
#pragma unroll
    for (int t = 0; t < 2; ++t)
#pragma unroll
        for (int c = 0; c < 8; ++c)
#pragma unroll
            for (int i = 0; i < 4; ++i) acc[t][c][i] = 0.f;
}

// ---------------- standalone K=128 GEMM (G3, G7) ----------------
template<bool BIAS, bool TANH_ACT, bool ADDEND, bool BNIN, bool STATS, bool STOREF, bool STOREB>
__global__ __launch_bounds__(256) void mgemm2(
    const __hip_bfloat16* __restrict__ A, const __hip_bfloat16* __restrict__ Wt, // [128][128]
    const float* __restrict__ bias, const float* __restrict__ addend,
    const float* __restrict__ scale, const float* __restrict__ shift,
    double* __restrict__ stats,
    float* __restrict__ outf, __hip_bfloat16* __restrict__ outb, int n) {
    __shared__ float ssum[128], ssq[128];
    const int tid = threadIdx.x, lane = tid & 63, wid = tid >> 6;
    const int l16 = lane & 15, lhi = lane >> 4;
    const int brow = blockIdx.x * 128 + wid * 32;
    if (STATS) {
        if (tid < 128) { ssum[tid] = 0.f; ssq[tid] = 0.f; }
        __syncthreads();
    }
    bf16x8 afr[4][2];
    lda_g<BNIN>(A, brow, l16, lhi, scale, shift, n, afr);
    f32x4 acc[2][8];
    zero_acc(acc);
    mm128<128>(afr, Wt, 0, l16, lhi, acc);
    epi<BIAS, TANH_ACT, ADDEND, STATS, STOREF, STOREB, false>(
        acc, brow, l16, lhi, bias, addend, ssum, ssq, outf, outb, nullptr, n);
    if (STATS) {
        __syncthreads();
        if (tid < 128) {
            atomicAdd(&stats[tid], (double)ssum[tid]);
            atomicAdd(&stats[128 + tid], (double)ssq[tid]);
        }
    }
}

// ---------------- F1: x -> h (store) -> U1 (store) ----------------
__global__ __launch_bounds__(256) void fused_in(
    const float* __restrict__ x, const __hip_bfloat16* __restrict__ WtIn,
    const float* __restrict__ b_in, const __hip_bfloat16* __restrict__ WtC1,
    __hip_bfloat16* __restrict__ hB, __hip_bfloat16* __restrict__ u1B, int n) {
    __shared__ __align__(16) char hlds[4 * 8192];   // per-wave 32x256B swizzled tile
    const int tid = threadIdx.x, lane = tid & 63, wid = tid >> 6;
    const int l16 = lane & 15, lhi = lane >> 4;
    const int brow = blockIdx.x * 128 + wid * 32;
    char* base = hlds + wid * 8192;

    // phase A: h = x @ WtIn + b_in   (K=64, f32 A)
    bf16x8 a64[2][2];
#pragma unroll
    for (int kk = 0; kk < 2; ++kk)
#pragma unroll
        for (int t = 0; t < 2; ++t) {
            int row = brow + t * 16 + l16; if (row > n - 1) row = n - 1;
            const float* p = x + (size_t)row * 64 + kk * 32 + lhi * 8;
            float4 u0 = *reinterpret_cast<const float4*>(p);
            float4 u1 = *reinterpret_cast<const float4*>(p + 4);
            bf16x8 a;
            a[0] = (__bf16)u0.x; a[1] = (__bf16)u0.y; a[2] = (__bf16)u0.z; a[3] = (__bf16)u0.w;
            a[4] = (__bf16)u1.x; a[5] = (__bf16)u1.y; a[6] = (__bf16)u1.z; a[7] = (__bf16)u1.w;
            a64[kk][t] = a;
        }
    f32x4 acc[2][8];
    zero_acc(acc);
#pragma unroll
    for (int kk = 0; kk < 2; ++kk)
#pragma unroll
        for (int c = 0; c < 8; ++c) {
            bf16x8 b = *reinterpret_cast<const bf16x8*>(
                WtIn + (size_t)(c * 16 + l16) * 64 + kk * 32 + lhi * 8);
            acc[0][c] = __builtin_amdgcn_mfma_f32_16x16x32_bf16(a64[kk][0], b, acc[0][c], 0, 0, 0);
            acc[1][c] = __builtin_amdgcn_mfma_f32_16x16x32_bf16(a64[kk][1], b, acc[1][c], 0, 0, 0);
        }
    epi<true, false, false, false, false, true, true>(
        acc, brow, l16, lhi, b_in, nullptr, nullptr, nullptr, nullptr, hB, base, n);
    __syncthreads();

    // phase B: U1 = h @ WtC1   (A from LDS)
    bf16x8 afr[4][2];
    lda_lds(base, l16, lhi, afr);
    zero_acc(acc);
    mm128<128>(afr, WtC1, 0, l16, lhi, acc);
    epi<false, false, false, false, false, true, false>(
        acc, brow, l16, lhi, nullptr, nullptr, nullptr, nullptr, nullptr, u1B, nullptr, n);
}

// ---------------- F2: [P|Q|z1] -> z2 -> z (store f32) -> M1 (store + stats) ----------------
__global__ __launch_bounds__(256) void fused_tail(
    const __hip_bfloat16* __restrict__ P, const __hip_bfloat16* __restrict__ Q,
    const __hip_bfloat16* __restrict__ z1,
    const __hip_bfloat16* __restrict__ Wt2, const float* __restrict__ b2cat,
    const __hip_bfloat16* __restrict__ WtZ, const float* __restrict__ bz,
    const __hip_bfloat16* __restrict__ WtM1, const float* __restrict__ bm1,
    double* __restrict__ stats,
    float* __restrict__ zout, __hip_bfloat16* __restrict__ m1B, int n) {
    __shared__ __align__(16) char tlds[4 * 8192];
    __shared__ float ssum[128], ssq[128];
    const int tid = threadIdx.x, lane = tid & 63, wid = tid >> 6;
    const int l16 = lane & 15, lhi = lane >> 4;
    const int brow = blockIdx.x * 128 + wid * 32;
    char* base = tlds + wid * 8192;
    if (tid < 128) { ssum[tid] = 0.f; ssq[tid] = 0.f; }
    __syncthreads();

    // phase A: z2 = tanh([P|Q|z1] @ Wt2 + b2cat)   (K=384)
    f32x4 acc[2][8];
    zero_acc(acc);
    const __hip_bfloat16* segs[3] = {P, Q, z1};
    bf16x8 afr[4][2];
#pragma unroll
    for (int s = 0; s < 3; ++s) {
        lda_g<false>(segs[s], brow, l16, lhi, nullptr, nullptr, n, afr);
        mm128<384>(afr, Wt2, s * 128, l16, lhi, acc);
    }
    epi<true, true, false, false, false, false, true>(
        acc, brow, l16, lhi, b2cat, nullptr, nullptr, nullptr, nullptr, nullptr, base, n);
    __syncthreads();

    // phase B: z = tanh(z2 @ WtZ + bz)  -> zout (f32) + LDS
    lda_lds(base, l16, lhi, afr);
    zero_acc(acc);
    mm128<128>(afr, WtZ, 0, l16, lhi, acc);
    __syncthreads();   // all LDS reads of z2 done before overwrite with z
    epi<true, true, false, false, true, false, true>(
        acc, brow, l16, lhi, bz, nullptr, nullptr, nullptr, zout, nullptr, base, n);
    __syncthreads();

    // phase C: M1 = z @ WtM1 + bm1 -> m1B + stats
    lda_lds(base, l16, lhi, afr);
    zero_acc(acc);
    mm128<128>(afr, WtM1, 0, l16, lhi, acc);
    epi<true, false, false, true, false, true, false>(
        acc, brow, l16, lhi, bm1, nullptr, ssum, ssq, nullptr, m1B, nullptr, n);
    __syncthreads();
    if (tid < 128) {
        atomicAdd(&stats[tid], (double)ssum[tid]);
        atomicAdd(&stats[128 + tid], (double)ssq[tid]);
    }
}

// BN finalize -> scale/shift form: relu(a*scale + shift)
__global__ void bn_finalize(const double* __restrict__ stats,
                            const float* __restrict__ g, const float* __restrict__ be,
                            float* __restrict__ scale, float* __restrict__ shift, int n) {
    int c = threadIdx.x;
    if (c < 128) {
        double m = stats[c] / (double)n;
        double var = stats[128 + c] / (double)n - m * m;
        float rs = rsqrtf((float)var + 1e-5f);
        float sc = g[c] * rs;
        scale[c] = sc;
        shift[c] = be[c] - (float)m * sc;
    }
}

// prob = sigmoid( relu(M2*scale+shift) @ Wm3 + bm3 )
__global__ void gemv_prob(const __hip_bfloat16* __restrict__ M2,
                          const float* __restrict__ scale, const float* __restrict__ shift,
                          const float* __restrict__ Wm3, const float* __restrict__ bm3,
                          float* __restrict__ outp, int n) {
    int wid = (int)((blockIdx.x * (size_t)blockDim.x + threadIdx.x) >> 6);
    int lane = threadIdx.x & 63;
    if (wid >= n) return;
    float s = 0.f;
#pragma unroll
    for (int t = 0; t < 2; ++t) {
        int k = lane + t * 64;
        float a = __bfloat162float(M2[(size_t)wid * 128 + k]);
        a = fmaxf(a * scale[k] + shift[k], 0.f);
        s += a * Wm3[k];
    }
#pragma unroll
    for (int off = 32; off > 0; off >>= 1) s += __shfl_down(s, off);
    if (lane == 0) outp[wid] = 1.f / (1.f + __expf(-(s + bm3[0])));
}

extern "C" void kernel_launch(void* const* d_in, const int* in_sizes, int n_in,
                              void* d_out, int out_size, void* d_ws, size_t ws_size,
                              hipStream_t stream) {
    const float* x   = (const float*)d_in[0];
    const int*   pos = (const int*)d_in[1];
    const int*   neg = (const int*)d_in[2];
    const float* W_in = (const float*)d_in[3];
    const float* b_in = (const float*)d_in[4];
    const float* W1p = (const float*)d_in[5];
    const float* b1p = (const float*)d_in[6];
    const float* W1n = (const float*)d_in[7];
    const float* b1n = (const float*)d_in[8];
    const float* W2p = (const float*)d_in[9];
    const float* b2p = (const float*)d_in[10];
    const float* W2n = (const float*)d_in[11];
    const float* b2n = (const float*)d_in[12];
    const float* Wz  = (const float*)d_in[13];
    const float* bz  = (const float*)d_in[14];
    const float* Wm1 = (const float*)d_in[15];
    const float* bm1 = (const float*)d_in[16];
    const float* g1  = (const float*)d_in[17];
    const float* be1 = (const float*)d_in[18];
    const float* Wm2 = (const float*)d_in[19];
    const float* bm2 = (const float*)d_in[20];
    const float* g2  = (const float*)d_in[21];
    const float* be2 = (const float*)d_in[22];
    const float* Wm3 = (const float*)d_in[23];
    const float* bm3 = (const float*)d_in[24];

    char* ws = (char*)d_ws;
    size_t off = 0;
    auto carve = [&](size_t bytes) -> void* {
        void* p = (void*)(ws + off);
        off = (off + bytes + 255) & ~(size_t)255;
        return p;
    };
    const size_t NB  = (size_t)NN * 128 * sizeof(float);
    const size_t NBH = (size_t)NN * 128 * sizeof(__hip_bfloat16);
    float* slot1 = (float*)carve(NB);                     // aggC f32; later aliased by P/Q bf16
    __hip_bfloat16* slotA = (__hip_bfloat16*)carve(NBH);  // hB
    __hip_bfloat16* slotB = (__hip_bfloat16*)carve(NBH);  // u1B -> m1B
    __hip_bfloat16* slotC = (__hip_bfloat16*)carve(NBH);  // z1B -> m2B
    int* cnt_p = (int*)carve(NN * sizeof(int));
    int* cnt_n = (int*)carve(NN * sizeof(int));
    int* off_p = (int*)carve(NN * sizeof(int));
    int* off_n = (int*)carve(NN * sizeof(int));
    int* cur_p = (int*)carve(NN * sizeof(int));
    int* cur_n = (int*)carve(NN * sizeof(int));
    int* csr_p = (int*)carve(EP * sizeof(int));
    int* csr_n = (int*)carve(EN * sizeof(int));
    int* bsum_p = (int*)carve(1024 * sizeof(int));
    int* bsum_n = (int*)carve(1024 * sizeof(int));
    __hip_bfloat16* WtIn = (__hip_bfloat16*)carve(128 * 64 * 2);
    __hip_bfloat16* WtC1 = (__hip_bfloat16*)carve(128 * 128 * 2);
    __hip_bfloat16* WtL1 = (__hip_bfloat16*)carve(128 * 128 * 2);
    __hip_bfloat16* Wt2  = (__hip_bfloat16*)carve(128 * 384 * 2);
    __hip_bfloat16* WtZ  = (__hip_bfloat16*)carve(128 * 128 * 2);
    __hip_bfloat16* WtM1 = (__hip_bfloat16*)carve(128 * 128 * 2);
    __hip_bfloat16* WtM2 = (__hip_bfloat16*)carve(128 * 128 * 2);
    float* bcat1 = (float*)carve(128 * sizeof(float));
    float* b2cat = (float*)carve(128 * sizeof(float));
    double* stats1 = (double*)carve(256 * sizeof(double));
    double* stats2 = (double*)carve(256 * sizeof(double));
    float* scale1 = (float*)carve(128 * sizeof(float));
    float* shift1 = (float*)carve(128 * sizeof(float));
    float* scale2 = (float*)carve(128 * sizeof(float));
    float* shift2 = (float*)carve(128 * sizeof(float));
    (void)ws_size; (void)in_sizes; (void)n_in; (void)out_size;

    __hip_bfloat16* aggPb = (__hip_bfloat16*)slot1;       // alias: aggC dead after G3
    __hip_bfloat16* aggQb = aggPb + (size_t)NN * 128;

    float* zout = (float*)d_out;                 // N x 128 (fp32)
    float* pout = zout + (size_t)NN * 128;       // N

    const int GB = (NN + 127) / 128;             // 1172
    const int NBLK = (NN + SCAN_BS - 1) / SCAN_BS;

    // ---- CSR build + weight prep ----
    hipMemsetAsync(cnt_p, 0, NN * sizeof(int), stream);
    hipMemsetAsync(cnt_n, 0, NN * sizeof(int), stream);
    hipMemsetAsync(stats1, 0, 256 * sizeof(double), stream);
    hipMemsetAsync(stats2, 0, 256 * sizeof(double), stream);
    count_kernel<<<(EP + 255) / 256, 256, 0, stream>>>(pos + EP, EP, cnt_p);
    count_kernel<<<(EN + 255) / 256, 256, 0, stream>>>(neg + EN, EN, cnt_n);
    scan_block<<<NBLK, SCAN_BS, 0, stream>>>(cnt_p, NN, off_p, bsum_p);
    scan_block<<<NBLK, SCAN_BS, 0, stream>>>(cnt_n, NN, off_n, bsum_n);
    scan_bsum<<<1, SCAN_BS, 0, stream>>>(bsum_p, NBLK);
    scan_bsum<<<1, SCAN_BS, 0, stream>>>(bsum_n, NBLK);
    scan_add<<<NBLK, SCAN_BS, 0, stream>>>(bsum_p, NN, off_p, cur_p);
    scan_add<<<NBLK, SCAN_BS, 0, stream>>>(bsum_n, NN, off_n, cur_n);
    fill_csr<<<(EP + 255) / 256, 256, 0, stream>>>(pos, pos + EP, EP, cur_p, csr_p);
    fill_csr<<<(EN + 255) / 256, 256, 0, stream>>>(neg, neg + EN, EN, cur_n, csr_n);
    prep_weights<<<192, 256, 0, stream>>>(W_in, W1p, b1p, W1n, b1n, W2p, b2p, W2n, b2n,
                                          Wz, Wm1, Wm2,
                                          WtIn, WtC1, WtL1, Wt2, WtZ, WtM1, WtM2,
                                          bcat1, b2cat);

    // F1: x -> h (hB) -> U1 (u1B)
    fused_in<<<GB, 256, 0, stream>>>(x, WtIn, b_in, WtC1, slotA, slotB, NN);

    // aggC = [mean_pos(U1[:, :64]) | mean_neg(U1[:, 64:])] -> slot1 (f32)
    gather1v<<<(NN * 16 + 255) / 256, 256, 0, stream>>>(
        slotB, off_p, cnt_p, csr_p, off_n, cnt_n, csr_n, slot1);

    // G3: z1 = tanh(aggC + h @ WtL1 + bcat1) -> z1B (slotC)
    mgemm2<true, true, true, false, false, false, true><<<GB, 256, 0, stream>>>(
        slotA, WtL1, bcat1, slot1, nullptr, nullptr, nullptr, nullptr, slotC, NN);

    // P = mean_pos(z1), Q = mean_neg(z1) -> bf16, alias slot1
    gather2v<<<(NN * 32 + 255) / 256, 256, 0, stream>>>(
        slotC, off_p, cnt_p, csr_p, off_n, cnt_n, csr_n, aggPb, aggQb);

    // F2: [P|Q|z1] -> z2 -> z (zout) -> M1 (slotB) + stats1
    fused_tail<<<GB, 256, 0, stream>>>(
        aggPb, aggQb, slotC, Wt2, b2cat, WtZ, bz, WtM1, bm1, stats1, zout, slotB, NN);
    bn_finalize<<<1, 128, 0, stream>>>(stats1, g1, be1, scale1, shift1, NN);

    // G7: M2 = relu(BN(M1)) @ WtM2 + bm2 -> m2B (slotC) + stats2
    mgemm2<true, false, false, true, true, false, true><<<GB, 256, 0, stream>>>(
        slotB, WtM2, bm2, nullptr, scale1, shift1, stats2, nullptr, slotC, NN);
    bn_finalize<<<1, 128, 0, stream>>>(stats2, g2, be2, scale2, shift2, NN);

    // prob = sigmoid(relu(BN(M2)) @ Wm3 + bm3) -> d_out tail
    gemv_prob<<<(NN + 3) / 4, 256, 0, stream>>>(slotC, scale2, shift2, Wm3, bm3, pout, NN);
}